// Round 1
// baseline (3920.004 us; speedup 1.0000x reference)
//
#include <hip/hip_runtime.h>
#include <math.h>

#define BATCH 16
#define CIN   3
#define HH    224
#define WW    224
#define HW    (HH*WW)
#define COUT  128
#define TAPS  147   // 3*7*7
#define CAND  192
#define TK    192
#define TW    32
#define TH    8

// workspace layout (bytes)
#define WS_WSC  0u                                  // scaled weights 128*147 f32
#define WS_BSH  (WS_WSC + (unsigned)(COUT*TAPS*4))  // folded bias/shift, 128 f32 (+pad)
#define WS_TOP1 (WS_BSH + 512u)                     // per-pixel channel max, 16*50176 f32
#define WS_CIDX (WS_TOP1 + (unsigned)(BATCH*HW*4))  // candidate spatial idx, 16*192 i32
#define WS_CKEY (WS_CIDX + (unsigned)(BATCH*CAND*4))// rank keys, 16*192 u64
#define WS_C3V  (WS_CKEY + (unsigned)(BATCH*CAND*8))
#define WS_C3I  (WS_C3V + (unsigned)(BATCH*CAND*3*4))

// ---- prep: fold BN scale into weights, compute per-channel shift ----
__global__ void prep_kernel(const float* __restrict__ w, const float* __restrict__ cb,
                            const float* __restrict__ gamma, const float* __restrict__ beta,
                            const float* __restrict__ mean, const float* __restrict__ var,
                            float* __restrict__ wsc, float* __restrict__ bsh) {
  int c = blockIdx.x;
  float s = gamma[c] * (1.0f / sqrtf(var[c] + 1e-5f));
  int t = threadIdx.x;
  if (t < TAPS) wsc[c*TAPS + t] = w[c*TAPS + t] * s;
  if (t == 0)   bsh[c] = (cb[c] - mean[c]) * s + beta[c];
}

// ---- main pass: fused conv+BN+ReLU, keep only per-pixel channel max ----
__global__ __launch_bounds__(256, 2)
void conv_max_kernel(const float* __restrict__ x, const float* __restrict__ wsc,
                     const float* __restrict__ bsh, float* __restrict__ top1) {
  __shared__ float tile[CIN][TH+6][TW+8];   // 38 valid cols, padded to 40
  int b  = blockIdx.z;
  int w0 = blockIdx.x * TW, h0 = blockIdx.y * TH;
  const float* xb = x + (size_t)b * CIN * HW;

  for (int i = threadIdx.x; i < CIN*14*38; i += 256) {
    int c = i / (14*38);
    int r = (i / 38) % 14;
    int col = i % 38;
    int gh = h0 - 3 + r, gw = w0 - 3 + col;
    float val = 0.0f;
    if (gh >= 0 && gh < HH && gw >= 0 && gw < WW) val = xb[c*HW + gh*WW + gw];
    tile[c][r][col] = val;
  }
  __syncthreads();

  int tx = threadIdx.x & 31;
  int ty = threadIdx.x >> 5;

  float patch[TAPS];
#pragma unroll
  for (int c = 0; c < CIN; ++c)
#pragma unroll
    for (int kh = 0; kh < 7; ++kh)
#pragma unroll
      for (int kw = 0; kw < 7; ++kw)
        patch[c*49 + kh*7 + kw] = tile[c][ty + kh][tx + kw];

  float m = -1e30f;
  for (int ch = 0; ch < COUT; ch += 4) {
    const float* __restrict__ wp = wsc + ch*TAPS;
    float a0 = bsh[ch+0], a1 = bsh[ch+1], a2 = bsh[ch+2], a3 = bsh[ch+3];
#pragma unroll
    for (int t = 0; t < TAPS; ++t) {
      float p = patch[t];
      a0 = fmaf(wp[t],        p, a0);
      a1 = fmaf(wp[TAPS+t],   p, a1);
      a2 = fmaf(wp[2*TAPS+t], p, a2);
      a3 = fmaf(wp[3*TAPS+t], p, a3);
    }
    m = fmaxf(m, fmaxf(fmaxf(a0, a1), fmaxf(a2, a3)));
  }
  top1[(size_t)b*HW + (h0+ty)*WW + (w0+tx)] = fmaxf(m, 0.0f);
}

// ---- per-image: radix-threshold + compact + bitonic sort -> top-192 candidates ----
__global__ void select_kernel(const float* __restrict__ top1, int* __restrict__ cand) {
  int img = blockIdx.x, tid = threadIdx.x;   // 512 threads
  const float* v = top1 + (size_t)img * HW;
  __shared__ unsigned hist[1024];
  __shared__ unsigned long long keys[1024];
  __shared__ unsigned sG, scnt, sbin, sthr, snc;

  for (int i = tid; i < 1024; i += 512) hist[i] = 0u;
  __syncthreads();
  for (int i = tid; i < HW; i += 512) {
    unsigned ub = __float_as_uint(v[i]);     // values >= 0 -> bits monotonic
    atomicAdd(&hist[ub >> 21], 1u);
  }
  __syncthreads();
  if (tid == 0) {
    unsigned cum = 0; int T = 1023;
    for (; T >= 0; --T) { unsigned c = hist[T]; if (cum + c >= TK) break; cum += c; }
    if (T < 0) T = 0;
    sG = cum; scnt = hist[T]; sbin = (unsigned)T;
    sthr = ((unsigned)T) << 21;
  }
  __syncthreads();
  unsigned G = sG, cnt = scnt, binT = sbin;
  if (G + cnt > 1024u) {                     // refine threshold one level
    __syncthreads();
    for (int i = tid; i < 1024; i += 512) hist[i] = 0u;
    __syncthreads();
    for (int i = tid; i < HW; i += 512) {
      unsigned ub = __float_as_uint(v[i]);
      if ((ub >> 21) == binT) atomicAdd(&hist[(ub >> 11) & 0x3FFu], 1u);
    }
    __syncthreads();
    if (tid == 0) {
      unsigned cum = G; int T2 = 1023;
      for (; T2 >= 0; --T2) { unsigned c = hist[T2]; if (cum + c >= TK) break; cum += c; }
      if (T2 < 0) T2 = 0;
      sthr = (binT << 21) | (((unsigned)T2) << 11);
    }
    __syncthreads();
  }
  unsigned thr = sthr;
  if (tid == 0) snc = 0u;
  for (int i = tid; i < 1024; i += 512) keys[i] = 0ull;
  __syncthreads();
  for (int i = tid; i < HW; i += 512) {
    unsigned ub = __float_as_uint(v[i]);
    if (ub >= thr) {
      unsigned p = atomicAdd(&snc, 1u);
      if (p < 1024u) keys[p] = ((unsigned long long)ub << 32) | (unsigned)(~(unsigned)i);
    }
  }
  // bitonic sort, descending; key = (valbits, ~idx) -> ties give lower idx first
  for (unsigned kk = 2; kk <= 1024; kk <<= 1)
    for (unsigned j = kk >> 1; j > 0; j >>= 1) {
      __syncthreads();
      for (unsigned t = tid; t < 1024; t += 512) {
        unsigned ixj = t ^ j;
        if (ixj > t) {
          unsigned long long a = keys[t], b = keys[ixj];
          bool desc = ((t & kk) == 0);
          if ((a < b) == desc) { keys[t] = b; keys[ixj] = a; }
        }
      }
    }
  __syncthreads();
  if (tid < CAND) {
    unsigned long long key = keys[tid];
    cand[img*CAND + tid] = (key == 0ull) ? -1 : (int)(~(unsigned)(key & 0xFFFFFFFFull));
  }
}

// ---- fp64 recompute at candidates; bit-faithful fp32 BN chain; top3 channels ----
__global__ void refine_kernel(const float* __restrict__ x, const float* __restrict__ w,
                              const float* __restrict__ cb, const float* __restrict__ gamma,
                              const float* __restrict__ beta, const float* __restrict__ mean,
                              const float* __restrict__ var, const int* __restrict__ cand,
                              unsigned long long* __restrict__ ckey,
                              float* __restrict__ c3v, float* __restrict__ c3i) {
#pragma clang fp contract(off)
  int slot = blockIdx.x, img = blockIdx.y;
  int c = threadIdx.x;                       // 128 threads = channels
  int sidx = cand[img*CAND + slot];
  if (sidx < 0) {
    if (c == 0) {
      ckey[img*CAND + slot] = 0ull;
      for (int j = 0; j < 3; ++j) { c3v[(img*CAND+slot)*3+j] = 0.f; c3i[(img*CAND+slot)*3+j] = 0.f; }
    }
    return;
  }
  int h = sidx / WW, wq = sidx % WW;
  const float* xb = x + (size_t)img * CIN * HW;
  double acc = 0.0;
  for (int ci = 0; ci < CIN; ++ci)
    for (int kh = 0; kh < 7; ++kh) {
      int gh = h - 3 + kh;
      if (gh < 0 || gh >= HH) continue;
      for (int kw = 0; kw < 7; ++kw) {
        int gw = wq - 3 + kw;
        if (gw < 0 || gw >= WW) continue;
        acc = fma((double)xb[ci*HW + gh*WW + gw], (double)w[c*TAPS + ci*49 + kh*7 + kw], acc);
      }
    }
  float y = (float)acc;                      // conv rounded to fp32
  y = y + cb[c];                             // + bias (fp32, separate rounding)
  float s  = gamma[c] * (1.0f / sqrtf(var[c] + 1e-5f));
  float t1 = (y - mean[c]) * s;              // contract(off): no fused fma
  float z  = t1 + beta[c];
  z = fmaxf(z, 0.0f);

  __shared__ float zf[COUT];
  zf[c] = z;
  __syncthreads();
  if (c == 0) {
    float v0=-1.f, v1=-1.f, v2=-1.f; int i0=0, i1=0, i2=0;
    for (int i = 0; i < COUT; ++i) {         // strict > keeps lowest channel on ties
      float vv = zf[i];
      if      (vv > v0) { v2=v1;i2=i1; v1=v0;i1=i0; v0=vv;i0=i; }
      else if (vv > v1) { v2=v1;i2=i1; v1=vv;i1=i; }
      else if (vv > v2) { v2=vv;i2=i; }
    }
    int base = (img*CAND + slot)*3;
    c3v[base+0]=v0; c3v[base+1]=v1; c3v[base+2]=v2;
    c3i[base+0]=(float)i0; c3i[base+1]=(float)i1; c3i[base+2]=(float)i2;
    ckey[img*CAND + slot] =
        ((unsigned long long)__float_as_uint(v0) << 32) | (unsigned)(~(unsigned)sidx);
  }
}

// ---- final: sort 192 refined candidates, write all three outputs ----
__global__ void final_kernel(const unsigned long long* __restrict__ ckey, const int* __restrict__ cand,
                             const float* __restrict__ c3v, const float* __restrict__ c3i,
                             float* __restrict__ out) {
  int img = blockIdx.x, tid = threadIdx.x;   // 256 threads
  __shared__ unsigned long long k[256];
  __shared__ int pay[256];
  k[tid]  = (tid < CAND) ? ckey[img*CAND + tid] : 0ull;
  pay[tid] = tid;
  for (unsigned kk = 2; kk <= 256; kk <<= 1)
    for (unsigned j = kk >> 1; j > 0; j >>= 1) {
      __syncthreads();
      unsigned i = tid, ixj = i ^ j;
      if (ixj > i) {
        unsigned long long a = k[i], b = k[ixj];
        bool desc = ((i & kk) == 0);
        if ((a < b) == desc) {
          k[i] = b; k[ixj] = a;
          int p = pay[i]; pay[i] = pay[ixj]; pay[ixj] = p;
        }
      }
    }
  __syncthreads();
  if (tid < 128) {
    int slot = pay[tid];
    int sidx = cand[img*CAND + slot];
    out[12288 + img*128 + tid] = (float)sidx;          // idx [16,1,128]
    int base = (img*CAND + slot)*3;
    for (int j = 0; j < 3; ++j) {
      out[(img*3 + j)*128 + tid]        = c3i[base + j];   // reduced_idx3
      out[6144 + (img*3 + j)*128 + tid] = c3v[base + j];   // reduced_top3
    }
  }
}

extern "C" void kernel_launch(void* const* d_in, const int* in_sizes, int n_in,
                              void* d_out, int out_size, void* d_ws, size_t ws_size,
                              hipStream_t stream) {
  const float* x     = (const float*)d_in[0];
  const float* w     = (const float*)d_in[1];
  const float* cb    = (const float*)d_in[2];
  const float* gamma = (const float*)d_in[3];
  const float* beta  = (const float*)d_in[4];
  const float* mean  = (const float*)d_in[5];
  const float* var   = (const float*)d_in[6];
  float* out = (float*)d_out;
  char*  ws  = (char*)d_ws;

  float* wsc  = (float*)(ws + WS_WSC);
  float* bsh  = (float*)(ws + WS_BSH);
  float* top1 = (float*)(ws + WS_TOP1);
  int*   cidx = (int*)(ws + WS_CIDX);
  unsigned long long* ck = (unsigned long long*)(ws + WS_CKEY);
  float* c3v = (float*)(ws + WS_C3V);
  float* c3i = (float*)(ws + WS_C3I);

  prep_kernel<<<COUT, 160, 0, stream>>>(w, cb, gamma, beta, mean, var, wsc, bsh);
  conv_max_kernel<<<dim3(WW/TW, HH/TH, BATCH), 256, 0, stream>>>(x, wsc, bsh, top1);
  select_kernel<<<BATCH, 512, 0, stream>>>(top1, cidx);
  refine_kernel<<<dim3(CAND, BATCH), COUT, 0, stream>>>(x, w, cb, gamma, beta, mean, var,
                                                        cidx, ck, c3v, c3i);
  final_kernel<<<BATCH, 256, 0, stream>>>(ck, cidx, c3v, c3i, out);
}

// Round 2
// 461.849 us; speedup vs baseline: 8.4876x; 8.4876x over previous
//
#include <hip/hip_runtime.h>
#include <math.h>

#define BATCH 16
#define CIN   3
#define HH    224
#define WW    224
#define HW    (HH*WW)
#define COUT  128
#define TAPS  147   // 3*7*7
#define CAND  192
#define TK    192
#define TW    32
#define TH    8
#define NCH   32    // channels accumulated per register block

// workspace layout (bytes)
#define WS_WSC  0u                                  // tap-major scaled weights 147*128 f32
#define WS_BSH  (WS_WSC + (unsigned)(COUT*TAPS*4))  // folded bias/shift, 128 f32 (+pad)
#define WS_TOP1 (WS_BSH + 512u)                     // per-pixel channel max, 16*50176 f32
#define WS_CIDX (WS_TOP1 + (unsigned)(BATCH*HW*4))  // candidate spatial idx, 16*192 i32
#define WS_CKEY (WS_CIDX + (unsigned)(BATCH*CAND*4))// rank keys, 16*192 u64
#define WS_C3V  (WS_CKEY + (unsigned)(BATCH*CAND*8))
#define WS_C3I  (WS_C3V + (unsigned)(BATCH*CAND*3*4))

// ---- prep: fold BN scale into weights (tap-major transpose), per-channel shift ----
__global__ void prep_kernel(const float* __restrict__ w, const float* __restrict__ cb,
                            const float* __restrict__ gamma, const float* __restrict__ beta,
                            const float* __restrict__ mean, const float* __restrict__ var,
                            float* __restrict__ wscT, float* __restrict__ bsh) {
  int c = blockIdx.x;
  float s = gamma[c] * (1.0f / sqrtf(var[c] + 1e-5f));
  int t = threadIdx.x;
  if (t < TAPS) wscT[t*COUT + c] = w[c*TAPS + t] * s;   // tap-major: wscT[t][c]
  if (t == 0)   bsh[c] = (cb[c] - mean[c]) * s + beta[c];
}

// ---- main pass: fused conv+BN+ReLU, keep only per-pixel channel max ----
// 32-channel accumulator blocks in VGPRs; taps streamed from LDS (no patch array).
__global__ __launch_bounds__(256, 4)
void conv_max_kernel(const float* __restrict__ x, const float* __restrict__ wscT,
                     const float* __restrict__ bsh, float* __restrict__ top1) {
  __shared__ float tile[CIN][TH+6][TW+8];   // 38 valid cols, padded to 40 (2 lanes/bank: free)
  int b  = blockIdx.z;
  int w0 = blockIdx.x * TW, h0 = blockIdx.y * TH;
  const float* xb = x + (size_t)b * CIN * HW;

  for (int i = threadIdx.x; i < CIN*14*38; i += 256) {
    int c = i / (14*38);
    int r = (i / 38) % 14;
    int col = i % 38;
    int gh = h0 - 3 + r, gw = w0 - 3 + col;
    float val = 0.0f;
    if (gh >= 0 && gh < HH && gw >= 0 && gw < WW) val = xb[c*HW + gh*WW + gw];
    tile[c][r][col] = val;
  }
  __syncthreads();

  int tx = threadIdx.x & 31;
  int ty = threadIdx.x >> 5;

  float m = -1e30f;
  for (int cg = 0; cg < COUT; cg += NCH) {
    float acc[NCH];
#pragma unroll
    for (int j = 0; j < NCH; ++j) acc[j] = bsh[cg + j];          // uniform s_load
    for (int kh = 0; kh < 7; ++kh) {                              // runtime: keep code small
#pragma unroll
      for (int c = 0; c < CIN; ++c) {
#pragma unroll
        for (int kw = 0; kw < 7; ++kw) {
          float p = tile[c][ty + kh][tx + kw];                    // 1 ds_read_b32
          const float* __restrict__ wt = wscT + (c*49 + kh*7 + kw)*COUT + cg;  // uniform
#pragma unroll
          for (int j = 0; j < NCH; ++j) acc[j] = fmaf(wt[j], p, acc[j]);
        }
      }
    }
#pragma unroll
    for (int j = 0; j < NCH; ++j) m = fmaxf(m, acc[j]);
  }
  top1[(size_t)b*HW + (h0+ty)*WW + (w0+tx)] = fmaxf(m, 0.0f);
}

// ---- per-image: radix-threshold + compact + bitonic sort -> top-192 candidates ----
__global__ void select_kernel(const float* __restrict__ top1, int* __restrict__ cand) {
  int img = blockIdx.x, tid = threadIdx.x;   // 512 threads
  const float* v = top1 + (size_t)img * HW;
  __shared__ unsigned hist[1024];
  __shared__ unsigned long long keys[1024];
  __shared__ unsigned sG, scnt, sbin, sthr, snc;

  for (int i = tid; i < 1024; i += 512) hist[i] = 0u;
  __syncthreads();
  for (int i = tid; i < HW; i += 512) {
    unsigned ub = __float_as_uint(v[i]);     // values >= 0 -> bits monotonic
    atomicAdd(&hist[ub >> 21], 1u);
  }
  __syncthreads();
  if (tid == 0) {
    unsigned cum = 0; int T = 1023;
    for (; T >= 0; --T) { unsigned c = hist[T]; if (cum + c >= TK) break; cum += c; }
    if (T < 0) T = 0;
    sG = cum; scnt = hist[T]; sbin = (unsigned)T;
    sthr = ((unsigned)T) << 21;
  }
  __syncthreads();
  unsigned G = sG, cnt = scnt, binT = sbin;
  if (G + cnt > 1024u) {                     // refine threshold one level
    __syncthreads();
    for (int i = tid; i < 1024; i += 512) hist[i] = 0u;
    __syncthreads();
    for (int i = tid; i < HW; i += 512) {
      unsigned ub = __float_as_uint(v[i]);
      if ((ub >> 21) == binT) atomicAdd(&hist[(ub >> 11) & 0x3FFu], 1u);
    }
    __syncthreads();
    if (tid == 0) {
      unsigned cum = G; int T2 = 1023;
      for (; T2 >= 0; --T2) { unsigned c = hist[T2]; if (cum + c >= TK) break; cum += c; }
      if (T2 < 0) T2 = 0;
      sthr = (binT << 21) | (((unsigned)T2) << 11);
    }
    __syncthreads();
  }
  unsigned thr = sthr;
  if (tid == 0) snc = 0u;
  for (int i = tid; i < 1024; i += 512) keys[i] = 0ull;
  __syncthreads();
  for (int i = tid; i < HW; i += 512) {
    unsigned ub = __float_as_uint(v[i]);
    if (ub >= thr) {
      unsigned p = atomicAdd(&snc, 1u);
      if (p < 1024u) keys[p] = ((unsigned long long)ub << 32) | (unsigned)(~(unsigned)i);
    }
  }
  // bitonic sort, descending; key = (valbits, ~idx) -> ties give lower idx first
  for (unsigned kk = 2; kk <= 1024; kk <<= 1)
    for (unsigned j = kk >> 1; j > 0; j >>= 1) {
      __syncthreads();
      for (unsigned t = tid; t < 1024; t += 512) {
        unsigned ixj = t ^ j;
        if (ixj > t) {
          unsigned long long a = keys[t], b = keys[ixj];
          bool desc = ((t & kk) == 0);
          if ((a < b) == desc) { keys[t] = b; keys[ixj] = a; }
        }
      }
    }
  __syncthreads();
  if (tid < CAND) {
    unsigned long long key = keys[tid];
    cand[img*CAND + tid] = (key == 0ull) ? -1 : (int)(~(unsigned)(key & 0xFFFFFFFFull));
  }
}

// ---- fp64 recompute at candidates; bit-faithful fp32 BN chain; top3 channels ----
__global__ void refine_kernel(const float* __restrict__ x, const float* __restrict__ w,
                              const float* __restrict__ cb, const float* __restrict__ gamma,
                              const float* __restrict__ beta, const float* __restrict__ mean,
                              const float* __restrict__ var, const int* __restrict__ cand,
                              unsigned long long* __restrict__ ckey,
                              float* __restrict__ c3v, float* __restrict__ c3i) {
#pragma clang fp contract(off)
  int slot = blockIdx.x, img = blockIdx.y;
  int c = threadIdx.x;                       // 128 threads = channels
  int sidx = cand[img*CAND + slot];
  if (sidx < 0) {
    if (c == 0) {
      ckey[img*CAND + slot] = 0ull;
      for (int j = 0; j < 3; ++j) { c3v[(img*CAND+slot)*3+j] = 0.f; c3i[(img*CAND+slot)*3+j] = 0.f; }
    }
    return;
  }
  int h = sidx / WW, wq = sidx % WW;
  const float* xb = x + (size_t)img * CIN * HW;
  double acc = 0.0;
  for (int ci = 0; ci < CIN; ++ci)
    for (int kh = 0; kh < 7; ++kh) {
      int gh = h - 3 + kh;
      if (gh < 0 || gh >= HH) continue;
      for (int kw = 0; kw < 7; ++kw) {
        int gw = wq - 3 + kw;
        if (gw < 0 || gw >= WW) continue;
        acc = fma((double)xb[ci*HW + gh*WW + gw], (double)w[c*TAPS + ci*49 + kh*7 + kw], acc);
      }
    }
  float y = (float)acc;                      // conv rounded to fp32
  y = y + cb[c];                             // + bias (fp32, separate rounding)
  float s  = gamma[c] * (1.0f / sqrtf(var[c] + 1e-5f));
  float t1 = (y - mean[c]) * s;              // contract(off): no fused fma
  float z  = t1 + beta[c];
  z = fmaxf(z, 0.0f);

  __shared__ float zf[COUT];
  zf[c] = z;
  __syncthreads();
  if (c == 0) {
    float v0=-1.f, v1=-1.f, v2=-1.f; int i0=0, i1=0, i2=0;
    for (int i = 0; i < COUT; ++i) {         // strict > keeps lowest channel on ties
      float vv = zf[i];
      if      (vv > v0) { v2=v1;i2=i1; v1=v0;i1=i0; v0=vv;i0=i; }
      else if (vv > v1) { v2=v1;i2=i1; v1=vv;i1=i; }
      else if (vv > v2) { v2=vv;i2=i; }
    }
    int base = (img*CAND + slot)*3;
    c3v[base+0]=v0; c3v[base+1]=v1; c3v[base+2]=v2;
    c3i[base+0]=(float)i0; c3i[base+1]=(float)i1; c3i[base+2]=(float)i2;
    ckey[img*CAND + slot] =
        ((unsigned long long)__float_as_uint(v0) << 32) | (unsigned)(~(unsigned)sidx);
  }
}

// ---- final: sort 192 refined candidates, write all three outputs ----
__global__ void final_kernel(const unsigned long long* __restrict__ ckey, const int* __restrict__ cand,
                             const float* __restrict__ c3v, const float* __restrict__ c3i,
                             float* __restrict__ out) {
  int img = blockIdx.x, tid = threadIdx.x;   // 256 threads
  __shared__ unsigned long long k[256];
  __shared__ int pay[256];
  k[tid]  = (tid < CAND) ? ckey[img*CAND + tid] : 0ull;
  pay[tid] = tid;
  for (unsigned kk = 2; kk <= 256; kk <<= 1)
    for (unsigned j = kk >> 1; j > 0; j >>= 1) {
      __syncthreads();
      unsigned i = tid, ixj = i ^ j;
      if (ixj > i) {
        unsigned long long a = k[i], b = k[ixj];
        bool desc = ((i & kk) == 0);
        if ((a < b) == desc) {
          k[i] = b; k[ixj] = a;
          int p = pay[i]; pay[i] = pay[ixj]; pay[ixj] = p;
        }
      }
    }
  __syncthreads();
  if (tid < 128) {
    int slot = pay[tid];
    int sidx = cand[img*CAND + slot];
    out[12288 + img*128 + tid] = (float)sidx;          // idx [16,1,128]
    int base = (img*CAND + slot)*3;
    for (int j = 0; j < 3; ++j) {
      out[(img*3 + j)*128 + tid]        = c3i[base + j];   // reduced_idx3
      out[6144 + (img*3 + j)*128 + tid] = c3v[base + j];   // reduced_top3
    }
  }
}

extern "C" void kernel_launch(void* const* d_in, const int* in_sizes, int n_in,
                              void* d_out, int out_size, void* d_ws, size_t ws_size,
                              hipStream_t stream) {
  const float* x     = (const float*)d_in[0];
  const float* w     = (const float*)d_in[1];
  const float* cb    = (const float*)d_in[2];
  const float* gamma = (const float*)d_in[3];
  const float* beta  = (const float*)d_in[4];
  const float* mean  = (const float*)d_in[5];
  const float* var   = (const float*)d_in[6];
  float* out = (float*)d_out;
  char*  ws  = (char*)d_ws;

  float* wscT = (float*)(ws + WS_WSC);
  float* bsh  = (float*)(ws + WS_BSH);
  float* top1 = (float*)(ws + WS_TOP1);
  int*   cidx = (int*)(ws + WS_CIDX);
  unsigned long long* ck = (unsigned long long*)(ws + WS_CKEY);
  float* c3v = (float*)(ws + WS_C3V);
  float* c3i = (float*)(ws + WS_C3I);

  prep_kernel<<<COUT, 160, 0, stream>>>(w, cb, gamma, beta, mean, var, wscT, bsh);
  conv_max_kernel<<<dim3(WW/TW, HH/TH, BATCH), 256, 0, stream>>>(x, wscT, bsh, top1);
  select_kernel<<<BATCH, 512, 0, stream>>>(top1, cidx);
  refine_kernel<<<dim3(CAND, BATCH), COUT, 0, stream>>>(x, w, cb, gamma, beta, mean, var,
                                                        cidx, ck, c3v, c3i);
  final_kernel<<<BATCH, 256, 0, stream>>>(ck, cidx, c3v, c3i, out);
}

// Round 3
// 299.783 us; speedup vs baseline: 13.0762x; 1.5406x over previous
//
#include <hip/hip_runtime.h>
#include <math.h>

#define BATCH 16
#define CIN   3
#define HH    224
#define WW    224
#define HW    (HH*WW)
#define COUT  128
#define TAPS  147
#define CAND  192
#define TK    192

typedef __attribute__((ext_vector_type(8))) short bf16x8_t;
typedef __attribute__((ext_vector_type(4))) float f32x4_t;

// B layout: [term 2][g 24][ch 128][kw 8] bf16 ; term stride 24576 elems, 98304 B total
#define B_BYTES   98304u
#define XSTR      24            // f32 per x-tile row (16+7 used, pad)
#define XROWS     22
#define XT_ELEMS  (CIN*XROWS*XSTR)   // 1584
#define LDS_CONV  (B_BYTES + XT_ELEMS*4 + 1024)   // 98304+6336+1024 = 105664

// workspace layout (bytes)
#define WS_BG   0u
#define WS_BSH  (WS_BG + B_BYTES)
#define WS_TOP1 (WS_BSH + 512u)
#define WS_CIDX (WS_TOP1 + (unsigned)(BATCH*HW*4))
#define WS_CKEY (WS_CIDX + (unsigned)(BATCH*CAND*4))
#define WS_C3V  (WS_CKEY + (unsigned)(BATCH*CAND*8))
#define WS_C3I  (WS_C3V + (unsigned)(BATCH*CAND*3*4))

// ---- prep: fold BN scale into weights, truncate-split to bf16 hi/lo in B-frag layout ----
__global__ void prep_kernel(const float* __restrict__ w, const float* __restrict__ cb,
                            const float* __restrict__ gamma, const float* __restrict__ beta,
                            const float* __restrict__ mean, const float* __restrict__ var,
                            unsigned short* __restrict__ Bg, float* __restrict__ bsh) {
  int c = blockIdx.x;                 // 128
  int t = threadIdx.x;                // 192: g = t>>3 (0..23), kw = t&7
  float s = gamma[c] * (1.0f / sqrtf(var[c] + 1e-5f));
  int g = t >> 3, kw = t & 7;
  float wsv = 0.0f;
  if (g < 21 && kw < 7) {
    int cin = g / 7, kh = g % 7;
    wsv = w[c*TAPS + cin*49 + kh*7 + kw] * s;
  }
  unsigned u  = __float_as_uint(wsv);
  unsigned hi = u >> 16;
  float hf = __uint_as_float(u & 0xFFFF0000u);
  unsigned lo = __float_as_uint(wsv - hf) >> 16;
  int idx = (g*128 + c)*8 + kw;
  Bg[idx]         = (unsigned short)hi;
  Bg[24576 + idx] = (unsigned short)lo;
  if (t == 0) bsh[c] = (cb[c] - mean[c]) * s + beta[c];
}

// ---- main pass: MFMA bf16-triple-split conv+BN+ReLU -> per-pixel channel max ----
// block: 16h x 16w pixels x 128 ch, 512 threads (8 waves).
// wave: q=wv>>1 pixel-quarter (64 px = 4 M-frags), ch-half (wv&1) (64 ch = 4 N-frags).
__global__ __launch_bounds__(512, 2)
void conv_mfma_kernel(const float* __restrict__ x, const unsigned short* __restrict__ Bg,
                      const float* __restrict__ bsh, float* __restrict__ top1) {
  extern __shared__ char smem[];
  float* xt = (float*)(smem + B_BYTES);
  float* pmax = (float*)(smem + B_BYTES + XT_ELEMS*4);

  int tid = threadIdx.x;
  int lane = tid & 63, wv = tid >> 6;
  int l15 = lane & 15, l4 = lane >> 4;
  int q = wv >> 1, chh = wv & 1;
  int b = blockIdx.z, w0 = blockIdx.x*16, h0 = blockIdx.y*16;
  const float* xb = x + (size_t)b * CIN * HW;

  // stage B (L2 -> LDS), 96KB
  {
    const float4* Bg4 = (const float4*)Bg;
    float4* Bl4 = (float4*)smem;
    for (int i = tid; i < (int)(B_BYTES/16); i += 512) Bl4[i] = Bg4[i];
  }
  // stage x tile 3 x 22 x 24 (zero-padded)
  for (int i = tid; i < XT_ELEMS; i += 512) {
    int c = i / (XROWS*XSTR);
    int r = (i / XSTR) % XROWS;
    int col = i % XSTR;
    int gh = h0 + r - 3, gw = w0 + col - 3;
    float v = 0.0f;
    if (gh >= 0 && gh < HH && gw >= 0 && gw < WW) v = xb[c*HW + gh*WW + gw];
    xt[i] = v;
  }
  // bias for this lane's 4 channel fragments
  float bias_n[4];
#pragma unroll
  for (int n = 0; n < 4; ++n) bias_n[n] = bsh[chh*64 + n*16 + l15];

  __syncthreads();

  f32x4_t acc[4][4];
#pragma unroll
  for (int m = 0; m < 4; ++m)
#pragma unroll
    for (int n = 0; n < 4; ++n) acc[m][n] = (f32x4_t){0.f,0.f,0.f,0.f};

  const bf16x8_t* B8 = (const bf16x8_t*)smem;
  int blane = l4*128 + chh*64 + l15;

#pragma unroll
  for (int kf = 0; kf < 6; ++kf) {
    bf16x8_t Bh[4], Bl[4];
#pragma unroll
    for (int n = 0; n < 4; ++n) {
      Bh[n] = B8[kf*512 + blane + n*16];
      Bl[n] = B8[3072 + kf*512 + blane + n*16];
    }
    // per-lane octet (cin,kh) for this K-frag
    int g = kf*4 + l4;
    int cin = (g*37) >> 8;
    int kh = g - cin*7;
    int rowidx = (g < 21) ? (cin*XROWS + kh)*XSTR : 0;   // clamp pads in-tile (B=0 there)
#pragma unroll
    for (int m = 0; m < 4; ++m) {
      int xbi = rowidx + (q*4 + m)*XSTR + l15;
      float xv[8];
#pragma unroll
      for (int kw = 0; kw < 8; ++kw) xv[kw] = xt[xbi + kw];
      bf16x8_t ah, al;
#pragma unroll
      for (int j = 0; j < 8; ++j) {
        unsigned u = __float_as_uint(xv[j]);
        ah[j] = (short)(u >> 16);
        float hf = __uint_as_float(u & 0xFFFF0000u);
        al[j] = (short)(__float_as_uint(xv[j] - hf) >> 16);
      }
#pragma unroll
      for (int n = 0; n < 4; ++n)
        acc[m][n] = __builtin_amdgcn_mfma_f32_16x16x32_bf16(ah, Bh[n], acc[m][n], 0, 0, 0);
#pragma unroll
      for (int n = 0; n < 4; ++n)
        acc[m][n] = __builtin_amdgcn_mfma_f32_16x16x32_bf16(ah, Bl[n], acc[m][n], 0, 0, 0);
#pragma unroll
      for (int n = 0; n < 4; ++n)
        acc[m][n] = __builtin_amdgcn_mfma_f32_16x16x32_bf16(al, Bh[n], acc[m][n], 0, 0, 0);
    }
  }

  // epilogue: +bias, max over channels
  float pmr[4][4];
#pragma unroll
  for (int m = 0; m < 4; ++m)
#pragma unroll
    for (int r = 0; r < 4; ++r) {
      float v = fmaxf(fmaxf(acc[m][0][r] + bias_n[0], acc[m][1][r] + bias_n[1]),
                      fmaxf(acc[m][2][r] + bias_n[2], acc[m][3][r] + bias_n[3]));
#pragma unroll
      for (int d = 1; d < 16; d <<= 1) v = fmaxf(v, __shfl_xor(v, d));
      pmr[m][r] = v;
    }
  if (!(wv & 1)) {
    if (l15 == 0) {
#pragma unroll
      for (int m = 0; m < 4; ++m)
#pragma unroll
        for (int r = 0; r < 4; ++r) pmax[q*64 + m*16 + l4*4 + r] = pmr[m][r];
    }
  }
  __syncthreads();
  if (wv & 1) {
    if (l15 == 0) {
#pragma unroll
      for (int m = 0; m < 4; ++m)
#pragma unroll
        for (int r = 0; r < 4; ++r) {
          int p = q*64 + m*16 + l4*4 + r;
          pmax[p] = fmaxf(pmax[p], pmr[m][r]);
        }
    }
  }
  __syncthreads();
  if (tid < 256) {
    float res = fmaxf(pmax[tid], 0.0f);
    top1[(size_t)b*HW + (h0 + (tid>>4))*WW + (w0 + (tid & 15))] = res;
  }
}

// ---- per-image: radix-threshold (parallel scans) + compact + bitonic sort -> top-192 ----
__global__ void select_kernel(const float* __restrict__ top1, int* __restrict__ cand) {
  int img = blockIdx.x, tid = threadIdx.x;   // 512 threads
  const float* v = top1 + (size_t)img * HW;
  __shared__ unsigned hist[1024];
  __shared__ unsigned long long keys[1024];
  __shared__ unsigned sG, scnt, sbin, sthr, snc;

  for (int i = tid; i < 1024; i += 512) hist[i] = 0u;
  __syncthreads();
  for (int i = tid; i < HW; i += 512)
    atomicAdd(&hist[__float_as_uint(v[i]) >> 21], 1u);
  __syncthreads();
  if (tid < 64) {                            // wave-parallel threshold find
    int j = tid;
    unsigned s = 0;
#pragma unroll
    for (int i = 0; i < 16; ++i) s += hist[j*16 + i];
    unsigned a = s;
#pragma unroll
    for (int d = 1; d < 64; d <<= 1) { unsigned t = __shfl_down(a, d); if (j + d < 64) a += t; }
    unsigned above = a - s;
    if (above < TK && a >= TK) {
      unsigned cum = above;
      for (int i = 15; i >= 0; --i) {
        unsigned c = hist[j*16 + i];
        if (cum + c >= TK) { sG = cum; scnt = c; sbin = (unsigned)(j*16 + i); break; }
        cum += c;
      }
    }
    if (j == 0 && a < TK) { sG = 0; scnt = hist[0]; sbin = 0; }
  }
  __syncthreads();
  unsigned G = sG, cnt = scnt, binT = sbin;
  unsigned thr = binT << 21;
  if (G + cnt > 1024u) {                     // refine one level (bits 20..11)
    __syncthreads();
    for (int i = tid; i < 1024; i += 512) hist[i] = 0u;
    __syncthreads();
    for (int i = tid; i < HW; i += 512) {
      unsigned ub = __float_as_uint(v[i]);
      if ((ub >> 21) == binT) atomicAdd(&hist[(ub >> 11) & 0x3FFu], 1u);
    }
    __syncthreads();
    unsigned TK2 = TK - G;
    if (tid < 64) {
      int j = tid;
      unsigned s = 0;
#pragma unroll
      for (int i = 0; i < 16; ++i) s += hist[j*16 + i];
      unsigned a = s;
#pragma unroll
      for (int d = 1; d < 64; d <<= 1) { unsigned t = __shfl_down(a, d); if (j + d < 64) a += t; }
      unsigned above = a - s;
      if (above < TK2 && a >= TK2) {
        unsigned cum = above;
        for (int i = 15; i >= 0; --i) {
          unsigned c = hist[j*16 + i];
          if (cum + c >= TK2) { sthr = (binT << 21) | ((unsigned)(j*16 + i) << 11); break; }
          cum += c;
        }
      }
      if (j == 0 && a < TK2) sthr = binT << 21;
    }
    __syncthreads();
    thr = sthr;
  }
  if (tid == 0) snc = 0u;
  for (int i = tid; i < 1024; i += 512) keys[i] = 0ull;
  __syncthreads();
  for (int i = tid; i < HW; i += 512) {
    unsigned ub = __float_as_uint(v[i]);
    if (ub >= thr) {
      unsigned p = atomicAdd(&snc, 1u);
      if (p < 1024u) keys[p] = ((unsigned long long)ub << 32) | (unsigned)(~(unsigned)i);
    }
  }
  for (unsigned kk = 2; kk <= 1024; kk <<= 1)
    for (unsigned j = kk >> 1; j > 0; j >>= 1) {
      __syncthreads();
      for (unsigned t = tid; t < 1024; t += 512) {
        unsigned ixj = t ^ j;
        if (ixj > t) {
          unsigned long long a = keys[t], b = keys[ixj];
          bool desc = ((t & kk) == 0);
          if ((a < b) == desc) { keys[t] = b; keys[ixj] = a; }
        }
      }
    }
  __syncthreads();
  if (tid < CAND) {
    unsigned long long key = keys[tid];
    cand[img*CAND + tid] = (key == 0ull) ? -1 : (int)(~(unsigned)(key & 0xFFFFFFFFull));
  }
}

// ---- fp64 recompute at candidates; bit-faithful fp32 BN chain; top3 channels ----
__global__ void refine_kernel(const float* __restrict__ x, const float* __restrict__ w,
                              const float* __restrict__ cb, const float* __restrict__ gamma,
                              const float* __restrict__ beta, const float* __restrict__ mean,
                              const float* __restrict__ var, const int* __restrict__ cand,
                              unsigned long long* __restrict__ ckey,
                              float* __restrict__ c3v, float* __restrict__ c3i) {
#pragma clang fp contract(off)
  int slot = blockIdx.x, img = blockIdx.y;
  int c = threadIdx.x;                       // 128 threads = channels
  int sidx = cand[img*CAND + slot];
  if (sidx < 0) {
    if (c == 0) {
      ckey[img*CAND + slot] = 0ull;
      for (int j = 0; j < 3; ++j) { c3v[(img*CAND+slot)*3+j] = 0.f; c3i[(img*CAND+slot)*3+j] = 0.f; }
    }
    return;
  }
  int h = sidx / WW, wq = sidx % WW;
  const float* xb = x + (size_t)img * CIN * HW;
  double acc = 0.0;
  for (int ci = 0; ci < CIN; ++ci)
    for (int kh = 0; kh < 7; ++kh) {
      int gh = h - 3 + kh;
      if (gh < 0 || gh >= HH) continue;
      for (int kw = 0; kw < 7; ++kw) {
        int gw = wq - 3 + kw;
        if (gw < 0 || gw >= WW) continue;
        acc = fma((double)xb[ci*HW + gh*WW + gw], (double)w[c*TAPS + ci*49 + kh*7 + kw], acc);
      }
    }
  float y = (float)acc;
  y = y + cb[c];
  float s  = gamma[c] * (1.0f / sqrtf(var[c] + 1e-5f));
  float t1 = (y - mean[c]) * s;
  float z  = t1 + beta[c];
  z = fmaxf(z, 0.0f);

  __shared__ float zf[COUT];
  zf[c] = z;
  __syncthreads();
  if (c == 0) {
    float v0=-1.f, v1=-1.f, v2=-1.f; int i0=0, i1=0, i2=0;
    for (int i = 0; i < COUT; ++i) {
      float vv = zf[i];
      if      (vv > v0) { v2=v1;i2=i1; v1=v0;i1=i0; v0=vv;i0=i; }
      else if (vv > v1) { v2=v1;i2=i1; v1=vv;i1=i; }
      else if (vv > v2) { v2=vv;i2=i; }
    }
    int base = (img*CAND + slot)*3;
    c3v[base+0]=v0; c3v[base+1]=v1; c3v[base+2]=v2;
    c3i[base+0]=(float)i0; c3i[base+1]=(float)i1; c3i[base+2]=(float)i2;
    ckey[img*CAND + slot] =
        ((unsigned long long)__float_as_uint(v0) << 32) | (unsigned)(~(unsigned)sidx);
  }
}

// ---- final: sort 192 refined candidates, write all three outputs ----
__global__ void final_kernel(const unsigned long long* __restrict__ ckey, const int* __restrict__ cand,
                             const float* __restrict__ c3v, const float* __restrict__ c3i,
                             float* __restrict__ out) {
  int img = blockIdx.x, tid = threadIdx.x;   // 256 threads
  __shared__ unsigned long long k[256];
  __shared__ int pay[256];
  k[tid]  = (tid < CAND) ? ckey[img*CAND + tid] : 0ull;
  pay[tid] = tid;
  for (unsigned kk = 2; kk <= 256; kk <<= 1)
    for (unsigned j = kk >> 1; j > 0; j >>= 1) {
      __syncthreads();
      unsigned i = tid, ixj = i ^ j;
      if (ixj > i) {
        unsigned long long a = k[i], b = k[ixj];
        bool desc = ((i & kk) == 0);
        if ((a < b) == desc) {
          k[i] = b; k[ixj] = a;
          int p = pay[i]; pay[i] = pay[ixj]; pay[ixj] = p;
        }
      }
    }
  __syncthreads();
  if (tid < 128) {
    int slot = pay[tid];
    int sidx = cand[img*CAND + slot];
    out[12288 + img*128 + tid] = (float)sidx;
    int base = (img*CAND + slot)*3;
    for (int j = 0; j < 3; ++j) {
      out[(img*3 + j)*128 + tid]        = c3i[base + j];
      out[6144 + (img*3 + j)*128 + tid] = c3v[base + j];
    }
  }
}

extern "C" void kernel_launch(void* const* d_in, const int* in_sizes, int n_in,
                              void* d_out, int out_size, void* d_ws, size_t ws_size,
                              hipStream_t stream) {
  const float* x     = (const float*)d_in[0];
  const float* w     = (const float*)d_in[1];
  const float* cb    = (const float*)d_in[2];
  const float* gamma = (const float*)d_in[3];
  const float* beta  = (const float*)d_in[4];
  const float* mean  = (const float*)d_in[5];
  const float* var   = (const float*)d_in[6];
  float* out = (float*)d_out;
  char*  ws  = (char*)d_ws;

  unsigned short* Bg = (unsigned short*)(ws + WS_BG);
  float* bsh  = (float*)(ws + WS_BSH);
  float* top1 = (float*)(ws + WS_TOP1);
  int*   cidx = (int*)(ws + WS_CIDX);
  unsigned long long* ck = (unsigned long long*)(ws + WS_CKEY);
  float* c3v = (float*)(ws + WS_C3V);
  float* c3i = (float*)(ws + WS_C3I);

  prep_kernel<<<COUT, 192, 0, stream>>>(w, cb, gamma, beta, mean, var, Bg, bsh);
  conv_mfma_kernel<<<dim3(WW/16, HH/16, BATCH), 512, LDS_CONV, stream>>>(x, Bg, bsh, top1);
  select_kernel<<<BATCH, 512, 0, stream>>>(top1, cidx);
  refine_kernel<<<dim3(CAND, BATCH), COUT, 0, stream>>>(x, w, cb, gamma, beta, mean, var,
                                                        cidx, ck, c3v, c3i);
  final_kernel<<<BATCH, 256, 0, stream>>>(ck, cidx, c3v, c3i, out);
}

// Round 4
// 256.406 us; speedup vs baseline: 15.2883x; 1.1692x over previous
//
#include <hip/hip_runtime.h>
#include <math.h>

#define BATCH 16
#define CIN   3
#define HH    224
#define WW    224
#define HW    (HH*WW)
#define COUT  128
#define TAPS  147
#define CAND  192
#define TK    192

typedef __attribute__((ext_vector_type(8))) short bf16x8_t;
typedef __attribute__((ext_vector_type(4))) float f32x4_t;

// B layout: [kf 6][term 2][oct 4][ch 128][kw 8] bf16 ; per-kf chunk = 16384 B
#define B_KF_BYTES 16384u
#define B_BYTES    98304u
#define XSTR      24            // f32 per x-tile row (16+7 used, pad)
#define XROWS     22
#define XT_ELEMS  (CIN*XROWS*XSTR)   // 1584
#define LDS_CONV  (2*B_KF_BYTES + XT_ELEMS*4)   // 32768+6336 = 39104

// workspace layout (bytes)
#define WS_BG   0u
#define WS_BSH  (WS_BG + B_BYTES)
#define WS_TOP1 (WS_BSH + 512u)
#define WS_CIDX (WS_TOP1 + (unsigned)(BATCH*HW*4))
#define WS_CKEY (WS_CIDX + (unsigned)(BATCH*CAND*4))
#define WS_C3V  (WS_CKEY + (unsigned)(BATCH*CAND*8))
#define WS_C3I  (WS_C3V + (unsigned)(BATCH*CAND*3*4))

typedef unsigned int u32;
__device__ __forceinline__ void gload_lds16(const u32* g, u32* l) {
  __builtin_amdgcn_global_load_lds((const __attribute__((address_space(1))) u32*)g,
                                   (__attribute__((address_space(3))) u32*)l, 16, 0, 0);
}

// ---- prep: fold BN scale, truncate-split to bf16 hi/lo, [kf][term][oct][ch][kw] ----
__global__ void prep_kernel(const float* __restrict__ w, const float* __restrict__ cb,
                            const float* __restrict__ gamma, const float* __restrict__ beta,
                            const float* __restrict__ mean, const float* __restrict__ var,
                            unsigned short* __restrict__ Bg, float* __restrict__ bsh) {
  int c = blockIdx.x;                 // 128
  int t = threadIdx.x;                // 192: g = t>>3 (0..23), kw = t&7
  float s = gamma[c] * (1.0f / sqrtf(var[c] + 1e-5f));
  int g = t >> 3, kw = t & 7;
  float wsv = 0.0f;
  if (g < 21 && kw < 7) {
    int cin = g / 7, kh = g % 7;
    wsv = w[c*TAPS + cin*49 + kh*7 + kw] * s;
  }
  unsigned u  = __float_as_uint(wsv);
  unsigned hi = u >> 16;
  float hf = __uint_as_float(u & 0xFFFF0000u);
  unsigned lo = __float_as_uint(wsv - hf) >> 16;
  int kf = g >> 2, oct = g & 3;
  Bg[(((kf*2+0)*4+oct)*128 + c)*8 + kw] = (unsigned short)hi;
  Bg[(((kf*2+1)*4+oct)*128 + c)*8 + kw] = (unsigned short)lo;
  if (t == 0) bsh[c] = (cb[c] - mean[c]) * s + beta[c];
}

// ---- main pass: MFMA bf16-triple-split conv+BN+ReLU -> per-pixel channel max ----
// block: 16h x 16w pixels x 128 ch, 512 threads (8 waves).
// B double-buffered per kf (16KB) via global_load_lds; x tile resident (6.3KB).
__global__ __launch_bounds__(512, 2)
void conv_mfma_kernel(const float* __restrict__ x, const unsigned short* __restrict__ Bg,
                      const float* __restrict__ bsh, float* __restrict__ top1) {
  extern __shared__ char smem[];
  char* bufs[2] = { smem, smem + B_KF_BYTES };
  float* xt = (float*)(smem + 2*B_KF_BYTES);

  int tid = threadIdx.x;
  int lane = tid & 63, wv = tid >> 6;
  int l15 = lane & 15, l4 = lane >> 4;
  int q = wv >> 1, chh = wv & 1;
  int b = blockIdx.z, w0 = blockIdx.x*16, h0 = blockIdx.y*16;
  const float* xb = x + (size_t)b * CIN * HW;
  const u32* Bg32 = (const u32*)Bg;

  // stage B chunk kf=0 into buf0 (async, 2 x 16B per thread)
  {
    const u32* src = Bg32;  // kf 0
#pragma unroll
    for (int k = 0; k < 2; ++k) {
      int off = (tid + k*512)*4;          // u32 units (16B per chunk)
      gload_lds16(src + off, (u32*)bufs[0] + off);
    }
  }
  // stage x tile 3 x 22 x 24 (zero-padded)
  for (int i = tid; i < XT_ELEMS; i += 512) {
    int c = i / (XROWS*XSTR);
    int r = (i / XSTR) % XROWS;
    int col = i % XSTR;
    int gh = h0 + r - 3, gw = w0 + col - 3;
    float v = 0.0f;
    if (gh >= 0 && gh < HH && gw >= 0 && gw < WW) v = xb[c*HW + gh*WW + gw];
    xt[i] = v;
  }
  // bias for this lane's 4 channel fragments
  float bias_n[4];
#pragma unroll
  for (int n = 0; n < 4; ++n) bias_n[n] = bsh[chh*64 + n*16 + l15];

  __syncthreads();   // drains vmcnt (B kf0 landed) + lgkm (x stores visible)

  f32x4_t acc[4][4];
#pragma unroll
  for (int m = 0; m < 4; ++m)
#pragma unroll
    for (int n = 0; n < 4; ++n) acc[m][n] = (f32x4_t){0.f,0.f,0.f,0.f};

  int blane = l4*128 + chh*64 + l15;

#pragma unroll
  for (int kf = 0; kf < 6; ++kf) {
    char* cur = bufs[kf & 1];
    char* nxt = bufs[(kf + 1) & 1];
    if (kf < 5) {                         // prefetch next B chunk (overlaps compute)
      const u32* src = Bg32 + (kf + 1)*(B_KF_BYTES/4);
#pragma unroll
      for (int k = 0; k < 2; ++k) {
        int off = (tid + k*512)*4;
        gload_lds16(src + off, (u32*)nxt + off);
      }
    }
    const bf16x8_t* B8 = (const bf16x8_t*)cur;
    bf16x8_t Bh[4], Bl[4];
#pragma unroll
    for (int n = 0; n < 4; ++n) {
      Bh[n] = B8[blane + n*16];
      Bl[n] = B8[512 + blane + n*16];
    }
    int g = kf*4 + l4;
    int cin = (g*37) >> 8;
    int kh = g - cin*7;
    int rowidx = (g < 21) ? (cin*XROWS + kh)*XSTR : 0;   // pads clamped in-tile (B=0 there)
#pragma unroll
    for (int m = 0; m < 4; ++m) {
      int xbi = rowidx + (q*4 + m)*XSTR + l15;
      float xv[8];
#pragma unroll
      for (int kw = 0; kw < 8; ++kw) xv[kw] = xt[xbi + kw];
      union { unsigned u[4]; bf16x8_t v; } AH, AL;
#pragma unroll
      for (int j = 0; j < 4; ++j) {
        unsigned u0 = __float_as_uint(xv[2*j]);
        unsigned u1 = __float_as_uint(xv[2*j+1]);
        AH.u[j] = __builtin_amdgcn_perm(u1, u0, 0x07060302u);
        float s0 = xv[2*j]   - __uint_as_float(u0 & 0xFFFF0000u);
        float s1 = xv[2*j+1] - __uint_as_float(u1 & 0xFFFF0000u);
        AL.u[j] = __builtin_amdgcn_perm(__float_as_uint(s1), __float_as_uint(s0), 0x07060302u);
      }
#pragma unroll
      for (int n = 0; n < 4; ++n)
        acc[m][n] = __builtin_amdgcn_mfma_f32_16x16x32_bf16(AH.v, Bh[n], acc[m][n], 0, 0, 0);
#pragma unroll
      for (int n = 0; n < 4; ++n)
        acc[m][n] = __builtin_amdgcn_mfma_f32_16x16x32_bf16(AH.v, Bl[n], acc[m][n], 0, 0, 0);
#pragma unroll
      for (int n = 0; n < 4; ++n)
        acc[m][n] = __builtin_amdgcn_mfma_f32_16x16x32_bf16(AL.v, Bh[n], acc[m][n], 0, 0, 0);
    }
    __syncthreads();   // all waves done reading cur; this wave's nxt loads drained
  }

  // epilogue: +bias, max over channels; pmax reuses B buffer space (safe post-barrier)
  float* pmax = (float*)smem;
  float pmr[4][4];
#pragma unroll
  for (int m = 0; m < 4; ++m)
#pragma unroll
    for (int r = 0; r < 4; ++r) {
      float v = fmaxf(fmaxf(acc[m][0][r] + bias_n[0], acc[m][1][r] + bias_n[1]),
                      fmaxf(acc[m][2][r] + bias_n[2], acc[m][3][r] + bias_n[3]));
#pragma unroll
      for (int d = 1; d < 16; d <<= 1) v = fmaxf(v, __shfl_xor(v, d));
      pmr[m][r] = v;
    }
  if (!(wv & 1)) {
    if (l15 == 0) {
#pragma unroll
      for (int m = 0; m < 4; ++m)
#pragma unroll
        for (int r = 0; r < 4; ++r) pmax[q*64 + m*16 + l4*4 + r] = pmr[m][r];
    }
  }
  __syncthreads();
  if (wv & 1) {
    if (l15 == 0) {
#pragma unroll
      for (int m = 0; m < 4; ++m)
#pragma unroll
        for (int r = 0; r < 4; ++r) {
          int p = q*64 + m*16 + l4*4 + r;
          pmax[p] = fmaxf(pmax[p], pmr[m][r]);
        }
    }
  }
  __syncthreads();
  if (tid < 256) {
    float res = fmaxf(pmax[tid], 0.0f);
    top1[(size_t)b*HW + (h0 + (tid>>4))*WW + (w0 + (tid & 15))] = res;
  }
}

// ---- per-image: radix-threshold + compact + bitonic sort -> top-192 candidates ----
#define SNT 1024
__global__ void select_kernel(const float* __restrict__ top1, int* __restrict__ cand) {
  int img = blockIdx.x, tid = threadIdx.x;   // 1024 threads
  const float* v = top1 + (size_t)img * HW;
  const float4* v4 = (const float4*)v;
  __shared__ unsigned hist[1024];
  __shared__ unsigned long long keys[1024];
  __shared__ unsigned sG, scnt, sbin, sthr, snc;

  hist[tid] = 0u;
  __syncthreads();
  for (int i = tid; i < HW/4; i += SNT) {
    float4 f = v4[i];
    atomicAdd(&hist[__float_as_uint(f.x) >> 21], 1u);
    atomicAdd(&hist[__float_as_uint(f.y) >> 21], 1u);
    atomicAdd(&hist[__float_as_uint(f.z) >> 21], 1u);
    atomicAdd(&hist[__float_as_uint(f.w) >> 21], 1u);
  }
  __syncthreads();
  if (tid < 64) {                            // wave-parallel threshold find
    int j = tid;
    unsigned s = 0;
#pragma unroll
    for (int i = 0; i < 16; ++i) s += hist[j*16 + i];
    unsigned a = s;
#pragma unroll
    for (int d = 1; d < 64; d <<= 1) { unsigned t = __shfl_down(a, d); if (j + d < 64) a += t; }
    unsigned above = a - s;
    if (above < TK && a >= TK) {
      unsigned cum = above;
      for (int i = 15; i >= 0; --i) {
        unsigned c = hist[j*16 + i];
        if (cum + c >= TK) { sG = cum; scnt = c; sbin = (unsigned)(j*16 + i); break; }
        cum += c;
      }
    }
    if (j == 0 && a < TK) { sG = 0; scnt = hist[0]; sbin = 0; }
  }
  __syncthreads();
  unsigned G = sG, cnt = scnt, binT = sbin;
  unsigned thr = binT << 21;
  if (G + cnt > 1024u) {                     // refine one level (bits 20..11)
    __syncthreads();
    hist[tid] = 0u;
    __syncthreads();
    for (int i = tid; i < HW/4; i += SNT) {
      float4 f = v4[i];
      float fv[4] = {f.x, f.y, f.z, f.w};
#pragma unroll
      for (int c = 0; c < 4; ++c) {
        unsigned ub = __float_as_uint(fv[c]);
        if ((ub >> 21) == binT) atomicAdd(&hist[(ub >> 11) & 0x3FFu], 1u);
      }
    }
    __syncthreads();
    unsigned TK2 = TK - G;
    if (tid < 64) {
      int j = tid;
      unsigned s = 0;
#pragma unroll
      for (int i = 0; i < 16; ++i) s += hist[j*16 + i];
      unsigned a = s;
#pragma unroll
      for (int d = 1; d < 64; d <<= 1) { unsigned t = __shfl_down(a, d); if (j + d < 64) a += t; }
      unsigned above = a - s;
      if (above < TK2 && a >= TK2) {
        unsigned cum = above;
        for (int i = 15; i >= 0; --i) {
          unsigned c = hist[j*16 + i];
          if (cum + c >= TK2) { sthr = (binT << 21) | ((unsigned)(j*16 + i) << 11); break; }
          cum += c;
        }
      }
      if (j == 0 && a < TK2) sthr = binT << 21;
    }
    __syncthreads();
    thr = sthr;
  }
  if (tid == 0) snc = 0u;
  keys[tid] = 0ull;
  __syncthreads();
  for (int i = tid; i < HW/4; i += SNT) {
    float4 f = v4[i];
    float fv[4] = {f.x, f.y, f.z, f.w};
#pragma unroll
    for (int c = 0; c < 4; ++c) {
      unsigned ub = __float_as_uint(fv[c]);
      if (ub >= thr) {
        unsigned p = atomicAdd(&snc, 1u);
        if (p < 1024u) keys[p] = ((unsigned long long)ub << 32) | (unsigned)(~(unsigned)(4*i + c));
      }
    }
  }
  // bitonic sort, descending; key = (valbits, ~idx) -> ties give lower idx first
  for (unsigned kk = 2; kk <= 1024; kk <<= 1)
    for (unsigned j = kk >> 1; j > 0; j >>= 1) {
      __syncthreads();
      unsigned t = tid, ixj = t ^ j;
      if (ixj > t) {
        unsigned long long a = keys[t], b = keys[ixj];
        bool desc = ((t & kk) == 0);
        if ((a < b) == desc) { keys[t] = b; keys[ixj] = a; }
      }
    }
  __syncthreads();
  if (tid < CAND) {
    unsigned long long key = keys[tid];
    cand[img*CAND + tid] = (key == 0ull) ? -1 : (int)(~(unsigned)(key & 0xFFFFFFFFull));
  }
}

// ---- fp64 recompute at candidates; bit-faithful fp32 BN chain; top3 channels ----
__global__ void refine_kernel(const float* __restrict__ x, const float* __restrict__ w,
                              const float* __restrict__ cb, const float* __restrict__ gamma,
                              const float* __restrict__ beta, const float* __restrict__ mean,
                              const float* __restrict__ var, const int* __restrict__ cand,
                              unsigned long long* __restrict__ ckey,
                              float* __restrict__ c3v, float* __restrict__ c3i) {
#pragma clang fp contract(off)
  int slot = blockIdx.x, img = blockIdx.y;
  int c = threadIdx.x;                       // 128 threads = channels
  int sidx = cand[img*CAND + slot];
  if (sidx < 0) {
    if (c == 0) {
      ckey[img*CAND + slot] = 0ull;
      for (int j = 0; j < 3; ++j) { c3v[(img*CAND+slot)*3+j] = 0.f; c3i[(img*CAND+slot)*3+j] = 0.f; }
    }
    return;
  }
  int h = sidx / WW, wq = sidx % WW;
  const float* xb = x + (size_t)img * CIN * HW;
  double acc = 0.0;
  for (int ci = 0; ci < CIN; ++ci)
    for (int kh = 0; kh < 7; ++kh) {
      int gh = h - 3 + kh;
      if (gh < 0 || gh >= HH) continue;
      for (int kw = 0; kw < 7; ++kw) {
        int gw = wq - 3 + kw;
        if (gw < 0 || gw >= WW) continue;
        acc = fma((double)xb[ci*HW + gh*WW + gw], (double)w[c*TAPS + ci*49 + kh*7 + kw], acc);
      }
    }
  float y = (float)acc;
  y = y + cb[c];
  float s  = gamma[c] * (1.0f / sqrtf(var[c] + 1e-5f));
  float t1 = (y - mean[c]) * s;
  float z  = t1 + beta[c];
  z = fmaxf(z, 0.0f);

  __shared__ float zf[COUT];
  zf[c] = z;
  __syncthreads();
  if (c == 0) {
    float v0=-1.f, v1=-1.f, v2=-1.f; int i0=0, i1=0, i2=0;
    for (int i = 0; i < COUT; ++i) {
      float vv = zf[i];
      if      (vv > v0) { v2=v1;i2=i1; v1=v0;i1=i0; v0=vv;i0=i; }
      else if (vv > v1) { v2=v1;i2=i1; v1=vv;i1=i; }
      else if (vv > v2) { v2=vv;i2=i; }
    }
    int base = (img*CAND + slot)*3;
    c3v[base+0]=v0; c3v[base+1]=v1; c3v[base+2]=v2;
    c3i[base+0]=(float)i0; c3i[base+1]=(float)i1; c3i[base+2]=(float)i2;
    ckey[img*CAND + slot] =
        ((unsigned long long)__float_as_uint(v0) << 32) | (unsigned)(~(unsigned)sidx);
  }
}

// ---- final: sort 192 refined candidates, write all three outputs ----
__global__ void final_kernel(const unsigned long long* __restrict__ ckey, const int* __restrict__ cand,
                             const float* __restrict__ c3v, const float* __restrict__ c3i,
                             float* __restrict__ out) {
  int img = blockIdx.x, tid = threadIdx.x;   // 256 threads
  __shared__ unsigned long long k[256];
  __shared__ int pay[256];
  k[tid]  = (tid < CAND) ? ckey[img*CAND + tid] : 0ull;
  pay[tid] = tid;
  for (unsigned kk = 2; kk <= 256; kk <<= 1)
    for (unsigned j = kk >> 1; j > 0; j >>= 1) {
      __syncthreads();
      unsigned i = tid, ixj = i ^ j;
      if (ixj > i) {
        unsigned long long a = k[i], b = k[ixj];
        bool desc = ((i & kk) == 0);
        if ((a < b) == desc) {
          k[i] = b; k[ixj] = a;
          int p = pay[i]; pay[i] = pay[ixj]; pay[ixj] = p;
        }
      }
    }
  __syncthreads();
  if (tid < 128) {
    int slot = pay[tid];
    int sidx = cand[img*CAND + slot];
    out[12288 + img*128 + tid] = (float)sidx;
    int base = (img*CAND + slot)*3;
    for (int j = 0; j < 3; ++j) {
      out[(img*3 + j)*128 + tid]        = c3i[base + j];
      out[6144 + (img*3 + j)*128 + tid] = c3v[base + j];
    }
  }
}

extern "C" void kernel_launch(void* const* d_in, const int* in_sizes, int n_in,
                              void* d_out, int out_size, void* d_ws, size_t ws_size,
                              hipStream_t stream) {
  const float* x     = (const float*)d_in[0];
  const float* w     = (const float*)d_in[1];
  const float* cb    = (const float*)d_in[2];
  const float* gamma = (const float*)d_in[3];
  const float* beta  = (const float*)d_in[4];
  const float* mean  = (const float*)d_in[5];
  const float* var   = (const float*)d_in[6];
  float* out = (float*)d_out;
  char*  ws  = (char*)d_ws;

  unsigned short* Bg = (unsigned short*)(ws + WS_BG);
  float* bsh  = (float*)(ws + WS_BSH);
  float* top1 = (float*)(ws + WS_TOP1);
  int*   cidx = (int*)(ws + WS_CIDX);
  unsigned long long* ck = (unsigned long long*)(ws + WS_CKEY);
  float* c3v = (float*)(ws + WS_C3V);
  float* c3i = (float*)(ws + WS_C3I);

  prep_kernel<<<COUT, 192, 0, stream>>>(w, cb, gamma, beta, mean, var, Bg, bsh);
  conv_mfma_kernel<<<dim3(WW/16, HH/16, BATCH), 512, LDS_CONV, stream>>>(x, Bg, bsh, top1);
  select_kernel<<<BATCH, SNT, 0, stream>>>(top1, cidx);
  refine_kernel<<<dim3(CAND, BATCH), COUT, 0, stream>>>(x, w, cb, gamma, beta, mean, var,
                                                        cidx, ck, c3v, c3i);
  final_kernel<<<BATCH, 256, 0, stream>>>(ck, cidx, c3v, c3i, out);
}

// Round 6
// 185.473 us; speedup vs baseline: 21.1351x; 1.3824x over previous
//
#include <hip/hip_runtime.h>
#include <math.h>

#define BATCH 16
#define CIN   3
#define HH    224
#define WW    224
#define HW    (HH*WW)
#define COUT  128
#define TAPS  147
#define CAND  192
#define TK    192

typedef __attribute__((ext_vector_type(8))) _Float16 f16x8_t;
typedef decltype(__builtin_amdgcn_cvt_pkrtz(0.f, 0.f)) f16x2_t;
typedef __attribute__((ext_vector_type(4))) float f32x4_t;

// B layout: [kf 6][oct 4][ch 128][kw 8] f16 ; 24576 f16 = 49152 B
#define B_BYTES   49152u
#define XSTR      24            // f32 per x-tile row (16+7 used, pad)
#define XROWS     22
#define XT_ELEMS  (CIN*XROWS*XSTR)   // 1584
#define LDS_CONV  (B_BYTES + XT_ELEMS*4 + 1024)   // 49152+6336+1024 = 56512

// workspace layout (bytes)
#define WS_BG   0u
#define WS_BSH  (WS_BG + B_BYTES)
#define WS_TOP1 (WS_BSH + 512u)
#define WS_CIDX (WS_TOP1 + (unsigned)(BATCH*HW*4))
#define WS_CKEY (WS_CIDX + (unsigned)(BATCH*CAND*4))
#define WS_C3V  (WS_CKEY + (unsigned)(BATCH*CAND*8))
#define WS_C3I  (WS_C3V + (unsigned)(BATCH*CAND*3*4))

typedef unsigned int u32;
__device__ __forceinline__ void gload_lds16(const u32* g, u32* l) {
  __builtin_amdgcn_global_load_lds((const __attribute__((address_space(1))) u32*)g,
                                   (__attribute__((address_space(3))) u32*)l, 16, 0, 0);
}

// ---- prep: fold BN scale into weights, fp16 (RN), [kf][oct][ch][kw] ----
__global__ void prep_kernel(const float* __restrict__ w, const float* __restrict__ cb,
                            const float* __restrict__ gamma, const float* __restrict__ beta,
                            const float* __restrict__ mean, const float* __restrict__ var,
                            unsigned short* __restrict__ Bg, float* __restrict__ bsh) {
  int c = blockIdx.x;                 // 128
  int t = threadIdx.x;                // 192: g = t>>3 (0..23), kw = t&7
  float s = gamma[c] * (1.0f / sqrtf(var[c] + 1e-5f));
  int g = t >> 3, kw = t & 7;
  float wsv = 0.0f;
  if (g < 21 && kw < 7) {
    int cin = g / 7, kh = g % 7;
    wsv = w[c*TAPS + cin*49 + kh*7 + kw] * s;
  }
  union { _Float16 h; unsigned short u; } cvt;
  cvt.h = (_Float16)wsv;              // round-to-nearest-even
  Bg[(g*128 + c)*8 + kw] = cvt.u;
  if (t == 0) bsh[c] = (cb[c] - mean[c]) * s + beta[c];
}

// ---- main pass: fp16 MFMA conv+BN+ReLU -> per-pixel channel max ----
// block: 16h x 16w pixels x 128 ch, 512 threads (8 waves).
// whole B (48KB) resident in LDS; x tile f32 (6.3KB); no barriers in K-loop.
__global__ __launch_bounds__(512, 4)
void conv_mfma_kernel(const float* __restrict__ x, const unsigned short* __restrict__ Bg,
                      const float* __restrict__ bsh, float* __restrict__ top1) {
  extern __shared__ char smem[];
  float* xt = (float*)(smem + B_BYTES);
  float* pmax = (float*)(smem + B_BYTES + XT_ELEMS*4);

  int tid = threadIdx.x;
  int lane = tid & 63, wv = tid >> 6;
  int l15 = lane & 15, l4 = lane >> 4;
  int q = wv >> 1, chh = wv & 1;
  int b = blockIdx.z, w0 = blockIdx.x*16, h0 = blockIdx.y*16;
  const float* xb = x + (size_t)b * CIN * HW;
  const u32* Bg32 = (const u32*)Bg;

  // stage whole B (async, 6 x 16B per thread: 512*6*16 = 49152)
#pragma unroll
  for (int k = 0; k < 6; ++k) {
    int off = (tid + k*512)*4;          // u32 units
    gload_lds16(Bg32 + off, (u32*)smem + off);
  }
  // stage x tile 3 x 22 x 24 (zero-padded), f32
  for (int i = tid; i < XT_ELEMS; i += 512) {
    int c = i / (XROWS*XSTR);
    int r = (i / XSTR) % XROWS;
    int col = i % XSTR;
    int gh = h0 + r - 3, gw = w0 + col - 3;
    float v = 0.0f;
    if (gh >= 0 && gh < HH && gw >= 0 && gw < WW) v = xb[c*HW + gh*WW + gw];
    xt[i] = v;
  }
  // bias for this lane's 4 channel fragments
  float bias_n[4];
#pragma unroll
  for (int n = 0; n < 4; ++n) bias_n[n] = bsh[chh*64 + n*16 + l15];

  __syncthreads();   // drains vmcnt (B landed) + lgkm (x stores visible)

  f32x4_t acc[4][4];
#pragma unroll
  for (int m = 0; m < 4; ++m)
#pragma unroll
    for (int n = 0; n < 4; ++n) acc[m][n] = (f32x4_t){0.f,0.f,0.f,0.f};

  const f16x8_t* B8 = (const f16x8_t*)smem;
  int blane = l4*128 + chh*64 + l15;

#pragma unroll
  for (int kf = 0; kf < 6; ++kf) {
    f16x8_t Bn[4];
#pragma unroll
    for (int n = 0; n < 4; ++n) Bn[n] = B8[kf*512 + blane + n*16];
    int g = kf*4 + l4;
    int cin = (g*37) >> 8;
    int kh = g - cin*7;
    int rowidx = (g < 21) ? (cin*XROWS + kh)*XSTR : 0;   // pads clamped in-tile (B=0 there)
#pragma unroll
    for (int m = 0; m < 4; ++m) {
      int xbi = rowidx + (q*4 + m)*XSTR + l15;
      float xv[8];
#pragma unroll
      for (int kw = 0; kw < 8; ++kw) xv[kw] = xt[xbi + kw];
      union { f16x2_t p[4]; f16x8_t v; } A;
#pragma unroll
      for (int j = 0; j < 4; ++j)
        A.p[j] = __builtin_amdgcn_cvt_pkrtz(xv[2*j], xv[2*j+1]);
#pragma unroll
      for (int n = 0; n < 4; ++n)
        acc[m][n] = __builtin_amdgcn_mfma_f32_16x16x32_f16(A.v, Bn[n], acc[m][n], 0, 0, 0);
    }
  }

  // epilogue: +bias, max over channels
  float pmr[4][4];
#pragma unroll
  for (int m = 0; m < 4; ++m)
#pragma unroll
    for (int r = 0; r < 4; ++r) {
      float v = fmaxf(fmaxf(acc[m][0][r] + bias_n[0], acc[m][1][r] + bias_n[1]),
                      fmaxf(acc[m][2][r] + bias_n[2], acc[m][3][r] + bias_n[3]));
#pragma unroll
      for (int d = 1; d < 16; d <<= 1) v = fmaxf(v, __shfl_xor(v, d));
      pmr[m][r] = v;
    }
  __syncthreads();
  if (!(wv & 1)) {
    if (l15 == 0) {
#pragma unroll
      for (int m = 0; m < 4; ++m)
#pragma unroll
        for (int r = 0; r < 4; ++r) pmax[q*64 + m*16 + l4*4 + r] = pmr[m][r];
    }
  }
  __syncthreads();
  if (wv & 1) {
    if (l15 == 0) {
#pragma unroll
      for (int m = 0; m < 4; ++m)
#pragma unroll
        for (int r = 0; r < 4; ++r) {
          int p = q*64 + m*16 + l4*4 + r;
          pmax[p] = fmaxf(pmax[p], pmr[m][r]);
        }
    }
  }
  __syncthreads();
  if (tid < 256) {
    float res = fmaxf(pmax[tid], 0.0f);
    top1[(size_t)b*HW + (h0 + (tid>>4))*WW + (w0 + (tid & 15))] = res;
  }
}

// ---- per-image: radix-threshold + compact + bitonic sort -> top-192 candidates ----
#define SNT 1024
__global__ void select_kernel(const float* __restrict__ top1, int* __restrict__ cand) {
  int img = blockIdx.x, tid = threadIdx.x;   // 1024 threads
  const float* v = top1 + (size_t)img * HW;
  const float4* v4 = (const float4*)v;
  __shared__ unsigned hist[1024];
  __shared__ unsigned long long keys[1024];
  __shared__ unsigned sG, scnt, sbin, sthr, snc;

  hist[tid] = 0u;
  __syncthreads();
  for (int i = tid; i < HW/4; i += SNT) {
    float4 f = v4[i];
    atomicAdd(&hist[__float_as_uint(f.x) >> 21], 1u);
    atomicAdd(&hist[__float_as_uint(f.y) >> 21], 1u);
    atomicAdd(&hist[__float_as_uint(f.z) >> 21], 1u);
    atomicAdd(&hist[__float_as_uint(f.w) >> 21], 1u);
  }
  __syncthreads();
  if (tid < 64) {                            // wave-parallel threshold find
    int j = tid;
    unsigned s = 0;
#pragma unroll
    for (int i = 0; i < 16; ++i) s += hist[j*16 + i];
    unsigned a = s;
#pragma unroll
    for (int d = 1; d < 64; d <<= 1) { unsigned t = __shfl_down(a, d); if (j + d < 64) a += t; }
    unsigned above = a - s;
    if (above < TK && a >= TK) {
      unsigned cum = above;
      for (int i = 15; i >= 0; --i) {
        unsigned c = hist[j*16 + i];
        if (cum + c >= TK) { sG = cum; scnt = c; sbin = (unsigned)(j*16 + i); break; }
        cum += c;
      }
    }
    if (j == 0 && a < TK) { sG = 0; scnt = hist[0]; sbin = 0; }
  }
  __syncthreads();
  unsigned G = sG, cnt = scnt, binT = sbin;
  unsigned thr = binT << 21;
  if (G + cnt > 1024u) {                     // refine one level (bits 20..11)
    __syncthreads();
    hist[tid] = 0u;
    __syncthreads();
    for (int i = tid; i < HW/4; i += SNT) {
      float4 f = v4[i];
      float fv[4] = {f.x, f.y, f.z, f.w};
#pragma unroll
      for (int c = 0; c < 4; ++c) {
        unsigned ub = __float_as_uint(fv[c]);
        if ((ub >> 21) == binT) atomicAdd(&hist[(ub >> 11) & 0x3FFu], 1u);
      }
    }
    __syncthreads();
    unsigned TK2 = TK - G;
    if (tid < 64) {
      int j = tid;
      unsigned s = 0;
#pragma unroll
      for (int i = 0; i < 16; ++i) s += hist[j*16 + i];
      unsigned a = s;
#pragma unroll
      for (int d = 1; d < 64; d <<= 1) { unsigned t = __shfl_down(a, d); if (j + d < 64) a += t; }
      unsigned above = a - s;
      if (above < TK2 && a >= TK2) {
        unsigned cum = above;
        for (int i = 15; i >= 0; --i) {
          unsigned c = hist[j*16 + i];
          if (cum + c >= TK2) { sthr = (binT << 21) | ((unsigned)(j*16 + i) << 11); break; }
          cum += c;
        }
      }
      if (j == 0 && a < TK2) sthr = binT << 21;
    }
    __syncthreads();
    thr = sthr;
  }
  if (tid == 0) snc = 0u;
  keys[tid] = 0ull;
  __syncthreads();
  for (int i = tid; i < HW/4; i += SNT) {
    float4 f = v4[i];
    float fv[4] = {f.x, f.y, f.z, f.w};
#pragma unroll
    for (int c = 0; c < 4; ++c) {
      unsigned ub = __float_as_uint(fv[c]);
      if (ub >= thr) {
        unsigned p = atomicAdd(&snc, 1u);
        if (p < 1024u) keys[p] = ((unsigned long long)ub << 32) | (unsigned)(~(unsigned)(4*i + c));
      }
    }
  }
  // bitonic sort, descending; key = (valbits, ~idx) -> ties give lower idx first
  for (unsigned kk = 2; kk <= 1024; kk <<= 1)
    for (unsigned j = kk >> 1; j > 0; j >>= 1) {
      __syncthreads();
      unsigned t = tid, ixj = t ^ j;
      if (ixj > t) {
        unsigned long long a = keys[t], b = keys[ixj];
        bool desc = ((t & kk) == 0);
        if ((a < b) == desc) { keys[t] = b; keys[ixj] = a; }
      }
    }
  __syncthreads();
  if (tid < CAND) {
    unsigned long long key = keys[tid];
    cand[img*CAND + tid] = (key == 0ull) ? -1 : (int)(~(unsigned)(key & 0xFFFFFFFFull));
  }
}

// ---- fp64 recompute at candidates; bit-faithful fp32 BN chain; top3 channels ----
__global__ void refine_kernel(const float* __restrict__ x, const float* __restrict__ w,
                              const float* __restrict__ cb, const float* __restrict__ gamma,
                              const float* __restrict__ beta, const float* __restrict__ mean,
                              const float* __restrict__ var, const int* __restrict__ cand,
                              unsigned long long* __restrict__ ckey,
                              float* __restrict__ c3v, float* __restrict__ c3i) {
#pragma clang fp contract(off)
  int slot = blockIdx.x, img = blockIdx.y;
  int c = threadIdx.x;                       // 128 threads = channels
  int sidx = cand[img*CAND + slot];
  if (sidx < 0) {
    if (c == 0) {
      ckey[img*CAND + slot] = 0ull;
      for (int j = 0; j < 3; ++j) { c3v[(img*CAND+slot)*3+j] = 0.f; c3i[(img*CAND+slot)*3+j] = 0.f; }
    }
    return;
  }
  int h = sidx / WW, wq = sidx % WW;
  const float* xb = x + (size_t)img * CIN * HW;
  double acc = 0.0;
  for (int ci = 0; ci < CIN; ++ci)
    for (int kh = 0; kh < 7; ++kh) {
      int gh = h - 3 + kh;
      if (gh < 0 || gh >= HH) continue;
      for (int kw = 0; kw < 7; ++kw) {
        int gw = wq - 3 + kw;
        if (gw < 0 || gw >= WW) continue;
        acc = fma((double)xb[ci*HW + gh*WW + gw], (double)w[c*TAPS + ci*49 + kh*7 + kw], acc);
      }
    }
  float y = (float)acc;
  y = y + cb[c];
  float s  = gamma[c] * (1.0f / sqrtf(var[c] + 1e-5f));
  float t1 = (y - mean[c]) * s;
  float z  = t1 + beta[c];
  z = fmaxf(z, 0.0f);

  __shared__ float zf[COUT];
  zf[c] = z;
  __syncthreads();
  if (c == 0) {
    float v0=-1.f, v1=-1.f, v2=-1.f; int i0=0, i1=0, i2=0;
    for (int i = 0; i < COUT; ++i) {
      float vv = zf[i];
      if      (vv > v0) { v2=v1;i2=i1; v1=v0;i1=i0; v0=vv;i0=i; }
      else if (vv > v1) { v2=v1;i2=i1; v1=vv;i1=i; }
      else if (vv > v2) { v2=vv;i2=i; }
    }
    int base = (img*CAND + slot)*3;
    c3v[base+0]=v0; c3v[base+1]=v1; c3v[base+2]=v2;
    c3i[base+0]=(float)i0; c3i[base+1]=(float)i1; c3i[base+2]=(float)i2;
    ckey[img*CAND + slot] =
        ((unsigned long long)__float_as_uint(v0) << 32) | (unsigned)(~(unsigned)sidx);
  }
}

// ---- final: sort 192 refined candidates, write all three outputs ----
__global__ void final_kernel(const unsigned long long* __restrict__ ckey, const int* __restrict__ cand,
                             const float* __restrict__ c3v, const float* __restrict__ c3i,
                             float* __restrict__ out) {
  int img = blockIdx.x, tid = threadIdx.x;   // 256 threads
  __shared__ unsigned long long k[256];
  __shared__ int pay[256];
  k[tid]  = (tid < CAND) ? ckey[img*CAND + tid] : 0ull;
  pay[tid] = tid;
  for (unsigned kk = 2; kk <= 256; kk <<= 1)
    for (unsigned j = kk >> 1; j > 0; j >>= 1) {
      __syncthreads();
      unsigned i = tid, ixj = i ^ j;
      if (ixj > i) {
        unsigned long long a = k[i], b = k[ixj];
        bool desc = ((i & kk) == 0);
        if ((a < b) == desc) {
          k[i] = b; k[ixj] = a;
          int p = pay[i]; pay[i] = pay[ixj]; pay[ixj] = p;
        }
      }
    }
  __syncthreads();
  if (tid < 128) {
    int slot = pay[tid];
    int sidx = cand[img*CAND + slot];
    out[12288 + img*128 + tid] = (float)sidx;
    int base = (img*CAND + slot)*3;
    for (int j = 0; j < 3; ++j) {
      out[(img*3 + j)*128 + tid]        = c3i[base + j];
      out[6144 + (img*3 + j)*128 + tid] = c3v[base + j];
    }
  }
}

extern "C" void kernel_launch(void* const* d_in, const int* in_sizes, int n_in,
                              void* d_out, int out_size, void* d_ws, size_t ws_size,
                              hipStream_t stream) {
  const float* x     = (const float*)d_in[0];
  const float* w     = (const float*)d_in[1];
  const float* cb    = (const float*)d_in[2];
  const float* gamma = (const float*)d_in[3];
  const float* beta  = (const float*)d_in[4];
  const float* mean  = (const float*)d_in[5];
  const float* var   = (const float*)d_in[6];
  float* out = (float*)d_out;
  char*  ws  = (char*)d_ws;

  unsigned short* Bg = (unsigned short*)(ws + WS_BG);
  float* bsh  = (float*)(ws + WS_BSH);
  float* top1 = (float*)(ws + WS_TOP1);
  int*   cidx = (int*)(ws + WS_CIDX);
  unsigned long long* ck = (unsigned long long*)(ws + WS_CKEY);
  float* c3v = (float*)(ws + WS_C3V);
  float* c3i = (float*)(ws + WS_C3I);

  prep_kernel<<<COUT, 192, 0, stream>>>(w, cb, gamma, beta, mean, var, Bg, bsh);
  conv_mfma_kernel<<<dim3(WW/16, HH/16, BATCH), 512, LDS_CONV, stream>>>(x, Bg, bsh, top1);
  select_kernel<<<BATCH, SNT, 0, stream>>>(top1, cidx);
  refine_kernel<<<dim3(CAND, BATCH), COUT, 0, stream>>>(x, w, cb, gamma, beta, mean, var,
                                                        cidx, ck, c3v, c3i);
  final_kernel<<<BATCH, 256, 0, stream>>>(ck, cidx, c3v, c3i, out);
}

// Round 7
// 118.827 us; speedup vs baseline: 32.9893x; 1.5609x over previous
//
#include <hip/hip_runtime.h>
#include <math.h>

#define BATCH 16
#define CIN   3
#define HH    224
#define WW    224
#define HW    (HH*WW)
#define COUT  128
#define TAPS  147
#define CAND  192
#define TK    192

typedef __attribute__((ext_vector_type(8))) _Float16 f16x8_t;
typedef decltype(__builtin_amdgcn_cvt_pkrtz(0.f, 0.f)) f16x2_t;
typedef __attribute__((ext_vector_type(4))) float f32x4_t;
typedef unsigned long long u64;

// B layout: [kf 6][oct 4][ch 128][kw 8] f16 ; 24576 f16 = 49152 B
#define B_BYTES   49152u
#define XSTR      24            // f32 per x-tile row (16+7 used, pad)
#define XROWS     22
#define XT_ELEMS  (CIN*XROWS*XSTR)   // 1584
#define LDS_CONV  (B_BYTES + XT_ELEMS*4 + 1024)   // 56512

// workspace layout (bytes)
#define WS_BG   0u
#define WS_BSH  (WS_BG + B_BYTES)
#define WS_TOP1 (WS_BSH + 512u)
#define WS_CIDX (WS_TOP1 + (unsigned)(BATCH*HW*4))
#define WS_CKEY (WS_CIDX + (unsigned)(BATCH*CAND*4))
#define WS_C3V  (WS_CKEY + (unsigned)(BATCH*CAND*8))
#define WS_C3I  (WS_C3V + (unsigned)(BATCH*CAND*3*4))
#define WS_WT   (WS_C3I + (unsigned)(BATCH*CAND*3*4))   // raw w, tap-major 147*128 f32

typedef unsigned int u32;
__device__ __forceinline__ void gload_lds16(const u32* g, u32* l) {
  __builtin_amdgcn_global_load_lds((const __attribute__((address_space(1))) u32*)g,
                                   (__attribute__((address_space(3))) u32*)l, 16, 0, 0);
}

// ---- prep: fp16 folded weights (B-frag layout) + raw tap-major wT + BN shift ----
__global__ void prep_kernel(const float* __restrict__ w, const float* __restrict__ cb,
                            const float* __restrict__ gamma, const float* __restrict__ beta,
                            const float* __restrict__ mean, const float* __restrict__ var,
                            unsigned short* __restrict__ Bg, float* __restrict__ bsh,
                            float* __restrict__ wT) {
  int c = blockIdx.x;                 // 128
  int t = threadIdx.x;                // 192: g = t>>3 (0..23), kw = t&7
  float s = gamma[c] * (1.0f / sqrtf(var[c] + 1e-5f));
  int g = t >> 3, kw = t & 7;
  float wraw = 0.0f;
  if (g < 21 && kw < 7) {
    wraw = w[c*TAPS + g*7 + kw];      // g = cin*7+kh, tap = g*7+kw
    wT[(g*7 + kw)*COUT + c] = wraw;   // raw, for fp64 refine (coalesced reads)
  }
  union { _Float16 h; unsigned short u; } cvt;
  cvt.h = (_Float16)(wraw * s);       // round-to-nearest-even
  Bg[(g*128 + c)*8 + kw] = cvt.u;
  if (t == 0) bsh[c] = (cb[c] - mean[c]) * s + beta[c];
}

// ---- main pass: fp16 MFMA conv+BN+ReLU -> per-pixel channel max ----
__global__ __launch_bounds__(512, 4)
void conv_mfma_kernel(const float* __restrict__ x, const unsigned short* __restrict__ Bg,
                      const float* __restrict__ bsh, float* __restrict__ top1) {
  extern __shared__ char smem[];
  float* xt = (float*)(smem + B_BYTES);
  float* pmax = (float*)(smem + B_BYTES + XT_ELEMS*4);

  int tid = threadIdx.x;
  int lane = tid & 63, wv = tid >> 6;
  int l15 = lane & 15, l4 = lane >> 4;
  int q = wv >> 1, chh = wv & 1;
  int b = blockIdx.z, w0 = blockIdx.x*16, h0 = blockIdx.y*16;
  const float* xb = x + (size_t)b * CIN * HW;
  const u32* Bg32 = (const u32*)Bg;

#pragma unroll
  for (int k = 0; k < 6; ++k) {
    int off = (tid + k*512)*4;
    gload_lds16(Bg32 + off, (u32*)smem + off);
  }
  for (int i = tid; i < XT_ELEMS; i += 512) {
    int c = i / (XROWS*XSTR);
    int r = (i / XSTR) % XROWS;
    int col = i % XSTR;
    int gh = h0 + r - 3, gw = w0 + col - 3;
    float v = 0.0f;
    if (gh >= 0 && gh < HH && gw >= 0 && gw < WW) v = xb[c*HW + gh*WW + gw];
    xt[i] = v;
  }
  float bias_n[4];
#pragma unroll
  for (int n = 0; n < 4; ++n) bias_n[n] = bsh[chh*64 + n*16 + l15];

  __syncthreads();

  f32x4_t acc[4][4];
#pragma unroll
  for (int m = 0; m < 4; ++m)
#pragma unroll
    for (int n = 0; n < 4; ++n) acc[m][n] = (f32x4_t){0.f,0.f,0.f,0.f};

  const f16x8_t* B8 = (const f16x8_t*)smem;
  int blane = l4*128 + chh*64 + l15;

#pragma unroll
  for (int kf = 0; kf < 6; ++kf) {
    f16x8_t Bn[4];
#pragma unroll
    for (int n = 0; n < 4; ++n) Bn[n] = B8[kf*512 + blane + n*16];
    int g = kf*4 + l4;
    int cin = (g*37) >> 8;
    int kh = g - cin*7;
    int rowidx = (g < 21) ? (cin*XROWS + kh)*XSTR : 0;
#pragma unroll
    for (int m = 0; m < 4; ++m) {
      int xbi = rowidx + (q*4 + m)*XSTR + l15;
      float xv[8];
#pragma unroll
      for (int kw = 0; kw < 8; ++kw) xv[kw] = xt[xbi + kw];
      union { f16x2_t p[4]; f16x8_t v; } A;
#pragma unroll
      for (int j = 0; j < 4; ++j)
        A.p[j] = __builtin_amdgcn_cvt_pkrtz(xv[2*j], xv[2*j+1]);
#pragma unroll
      for (int n = 0; n < 4; ++n)
        acc[m][n] = __builtin_amdgcn_mfma_f32_16x16x32_f16(A.v, Bn[n], acc[m][n], 0, 0, 0);
    }
  }

  float pmr[4][4];
#pragma unroll
  for (int m = 0; m < 4; ++m)
#pragma unroll
    for (int r = 0; r < 4; ++r) {
      float v = fmaxf(fmaxf(acc[m][0][r] + bias_n[0], acc[m][1][r] + bias_n[1]),
                      fmaxf(acc[m][2][r] + bias_n[2], acc[m][3][r] + bias_n[3]));
#pragma unroll
      for (int d = 1; d < 16; d <<= 1) v = fmaxf(v, __shfl_xor(v, d));
      pmr[m][r] = v;
    }
  __syncthreads();
  if (!(wv & 1)) {
    if (l15 == 0) {
#pragma unroll
      for (int m = 0; m < 4; ++m)
#pragma unroll
        for (int r = 0; r < 4; ++r) pmax[q*64 + m*16 + l4*4 + r] = pmr[m][r];
    }
  }
  __syncthreads();
  if (wv & 1) {
    if (l15 == 0) {
#pragma unroll
      for (int m = 0; m < 4; ++m)
#pragma unroll
        for (int r = 0; r < 4; ++r) {
          int p = q*64 + m*16 + l4*4 + r;
          pmax[p] = fmaxf(pmax[p], pmr[m][r]);
        }
    }
  }
  __syncthreads();
  if (tid < 256) {
    float res = fmaxf(pmax[tid], 0.0f);
    top1[(size_t)b*HW + (h0 + (tid>>4))*WW + (w0 + (tid & 15))] = res;
  }
}

// ---- per-image: radix-threshold + compact + bitonic sort -> top-192 candidates ----
#define SNT 1024
__global__ void select_kernel(const float* __restrict__ top1, int* __restrict__ cand) {
  int img = blockIdx.x, tid = threadIdx.x;   // 1024 threads
  const float* v = top1 + (size_t)img * HW;
  const float4* v4 = (const float4*)v;
  __shared__ unsigned hist[1024];
  __shared__ u64 keys[1024];
  __shared__ unsigned sG, scnt, sbin, sthr, snc;

  hist[tid] = 0u;
  __syncthreads();
  for (int i = tid; i < HW/4; i += SNT) {
    float4 f = v4[i];
    atomicAdd(&hist[__float_as_uint(f.x) >> 21], 1u);
    atomicAdd(&hist[__float_as_uint(f.y) >> 21], 1u);
    atomicAdd(&hist[__float_as_uint(f.z) >> 21], 1u);
    atomicAdd(&hist[__float_as_uint(f.w) >> 21], 1u);
  }
  __syncthreads();
  if (tid < 64) {
    int j = tid;
    unsigned s = 0;
#pragma unroll
    for (int i = 0; i < 16; ++i) s += hist[j*16 + i];
    unsigned a = s;
#pragma unroll
    for (int d = 1; d < 64; d <<= 1) { unsigned t = __shfl_down(a, d); if (j + d < 64) a += t; }
    unsigned above = a - s;
    if (above < TK && a >= TK) {
      unsigned cum = above;
      for (int i = 15; i >= 0; --i) {
        unsigned c = hist[j*16 + i];
        if (cum + c >= TK) { sG = cum; scnt = c; sbin = (unsigned)(j*16 + i); break; }
        cum += c;
      }
    }
    if (j == 0 && a < TK) { sG = 0; scnt = hist[0]; sbin = 0; }
  }
  __syncthreads();
  unsigned G = sG, cnt = scnt, binT = sbin;
  unsigned thr = binT << 21;
  if (G + cnt > 1024u) {
    __syncthreads();
    hist[tid] = 0u;
    __syncthreads();
    for (int i = tid; i < HW/4; i += SNT) {
      float4 f = v4[i];
      float fv[4] = {f.x, f.y, f.z, f.w};
#pragma unroll
      for (int c = 0; c < 4; ++c) {
        unsigned ub = __float_as_uint(fv[c]);
        if ((ub >> 21) == binT) atomicAdd(&hist[(ub >> 11) & 0x3FFu], 1u);
      }
    }
    __syncthreads();
    unsigned TK2 = TK - G;
    if (tid < 64) {
      int j = tid;
      unsigned s = 0;
#pragma unroll
      for (int i = 0; i < 16; ++i) s += hist[j*16 + i];
      unsigned a = s;
#pragma unroll
      for (int d = 1; d < 64; d <<= 1) { unsigned t = __shfl_down(a, d); if (j + d < 64) a += t; }
      unsigned above = a - s;
      if (above < TK2 && a >= TK2) {
        unsigned cum = above;
        for (int i = 15; i >= 0; --i) {
          unsigned c = hist[j*16 + i];
          if (cum + c >= TK2) { sthr = (binT << 21) | ((unsigned)(j*16 + i) << 11); break; }
          cum += c;
        }
      }
      if (j == 0 && a < TK2) sthr = binT << 21;
    }
    __syncthreads();
    thr = sthr;
  }
  if (tid == 0) snc = 0u;
  keys[tid] = 0ull;
  __syncthreads();
  for (int i = tid; i < HW/4; i += SNT) {
    float4 f = v4[i];
    float fv[4] = {f.x, f.y, f.z, f.w};
#pragma unroll
    for (int c = 0; c < 4; ++c) {
      unsigned ub = __float_as_uint(fv[c]);
      if (ub >= thr) {
        unsigned p = atomicAdd(&snc, 1u);
        if (p < 1024u) keys[p] = ((u64)ub << 32) | (unsigned)(~(unsigned)(4*i + c));
      }
    }
  }
  for (unsigned kk = 2; kk <= 1024; kk <<= 1)
    for (unsigned j = kk >> 1; j > 0; j >>= 1) {
      __syncthreads();
      unsigned t = tid, ixj = t ^ j;
      if (ixj > t) {
        u64 a = keys[t], b = keys[ixj];
        bool desc = ((t & kk) == 0);
        if ((a < b) == desc) { keys[t] = b; keys[ixj] = a; }
      }
    }
  __syncthreads();
  if (tid < CAND) {
    u64 key = keys[tid];
    cand[img*CAND + tid] = (key == 0ull) ? -1 : (int)(~(unsigned)(key & 0xFFFFFFFFull));
  }
}

// ---- fp64 recompute at candidates (coalesced wT, LDS x-patch, parallel top3) ----
__global__ void refine_kernel(const float* __restrict__ x, const float* __restrict__ wT,
                              const float* __restrict__ cb, const float* __restrict__ gamma,
                              const float* __restrict__ beta, const float* __restrict__ mean,
                              const float* __restrict__ var, const int* __restrict__ cand,
                              u64* __restrict__ ckey,
                              float* __restrict__ c3v, float* __restrict__ c3i) {
#pragma clang fp contract(off)
  int slot = blockIdx.x, img = blockIdx.y;
  int c = threadIdx.x;                       // 128 threads = channels
  int sidx = cand[img*CAND + slot];
  if (sidx < 0) {
    if (c == 0) {
      ckey[img*CAND + slot] = 0ull;
      for (int j = 0; j < 3; ++j) { c3v[(img*CAND+slot)*3+j] = 0.f; c3i[(img*CAND+slot)*3+j] = 0.f; }
    }
    return;
  }
  int h = sidx / WW, wq = sidx % WW;
  const float* xb = x + (size_t)img * CIN * HW;

  __shared__ float xs[TAPS + 13];            // zero-padded patch, tap order cin*49+kh*7+kw
  for (int t = c; t < TAPS; t += 128) {
    int cin = t / 49, r = t % 49;
    int kh = r / 7, kw = r % 7;
    int gh = h - 3 + kh, gw = wq - 3 + kw;
    float v = 0.0f;
    if (gh >= 0 && gh < HH && gw >= 0 && gw < WW) v = xb[cin*HW + gh*WW + gw];
    xs[t] = v;
  }
  __syncthreads();

  // fp64 dot in EXACT same tap order as before (pad contributes exact 0)
  double acc = 0.0;
#pragma unroll 7
  for (int t = 0; t < TAPS; ++t)
    acc = fma((double)xs[t], (double)wT[t*COUT + c], acc);

  float y = (float)acc;
  y = y + cb[c];
  float s  = gamma[c] * (1.0f / sqrtf(var[c] + 1e-5f));
  float t1 = (y - mean[c]) * s;
  float z  = t1 + beta[c];
  z = fmaxf(z, 0.0f);

  // parallel top-3: unique keys (valbits | (127-ch)) -> max = larger val, tie = lower ch
  __shared__ u64 zk[COUT];
  zk[c] = ((u64)__float_as_uint(z) << 32) | (unsigned)(127 - c);
  __syncthreads();
  if (c < 64) {
    u64 k0 = zk[c], k1 = zk[c + 64];
    int base = (img*CAND + slot)*3;
#pragma unroll
    for (int pick = 0; pick < 3; ++pick) {
      u64 m = (k0 > k1) ? k0 : k1;
#pragma unroll
      for (int d = 1; d < 64; d <<= 1) {
        u64 o = __shfl_xor((unsigned long long)m, d);
        if (o > m) m = o;
      }
      if (c == 0) {
        float vv = __uint_as_float((unsigned)(m >> 32));
        int ch = 127 - (int)(m & 0xFFFFFFFFull);
        c3v[base + pick] = vv;
        c3i[base + pick] = (float)ch;
        if (pick == 0)
          ckey[img*CAND + slot] = ((u64)(m >> 32) << 32) | (unsigned)(~(unsigned)sidx);
      }
      if (k0 == m) k0 = 0ull;
      if (k1 == m) k1 = 0ull;
    }
  }
}

// ---- final: sort 192 refined candidates, write all three outputs ----
__global__ void final_kernel(const u64* __restrict__ ckey, const int* __restrict__ cand,
                             const float* __restrict__ c3v, const float* __restrict__ c3i,
                             float* __restrict__ out) {
  int img = blockIdx.x, tid = threadIdx.x;   // 256 threads
  __shared__ u64 k[256];
  __shared__ int pay[256];
  k[tid]  = (tid < CAND) ? ckey[img*CAND + tid] : 0ull;
  pay[tid] = tid;
  for (unsigned kk = 2; kk <= 256; kk <<= 1)
    for (unsigned j = kk >> 1; j > 0; j >>= 1) {
      __syncthreads();
      unsigned i = tid, ixj = i ^ j;
      if (ixj > i) {
        u64 a = k[i], b = k[ixj];
        bool desc = ((i & kk) == 0);
        if ((a < b) == desc) {
          k[i] = b; k[ixj] = a;
          int p = pay[i]; pay[i] = pay[ixj]; pay[ixj] = p;
        }
      }
    }
  __syncthreads();
  if (tid < 128) {
    int slot = pay[tid];
    int sidx = cand[img*CAND + slot];
    out[12288 + img*128 + tid] = (float)sidx;
    int base = (img*CAND + slot)*3;
    for (int j = 0; j < 3; ++j) {
      out[(img*3 + j)*128 + tid]        = c3i[base + j];
      out[6144 + (img*3 + j)*128 + tid] = c3v[base + j];
    }
  }
}

extern "C" void kernel_launch(void* const* d_in, const int* in_sizes, int n_in,
                              void* d_out, int out_size, void* d_ws, size_t ws_size,
                              hipStream_t stream) {
  const float* x     = (const float*)d_in[0];
  const float* w     = (const float*)d_in[1];
  const float* cb    = (const float*)d_in[2];
  const float* gamma = (const float*)d_in[3];
  const float* beta  = (const float*)d_in[4];
  const float* mean  = (const float*)d_in[5];
  const float* var   = (const float*)d_in[6];
  float* out = (float*)d_out;
  char*  ws  = (char*)d_ws;

  unsigned short* Bg = (unsigned short*)(ws + WS_BG);
  float* bsh  = (float*)(ws + WS_BSH);
  float* top1 = (float*)(ws + WS_TOP1);
  int*   cidx = (int*)(ws + WS_CIDX);
  u64*   ck   = (u64*)(ws + WS_CKEY);
  float* c3v = (float*)(ws + WS_C3V);
  float* c3i = (float*)(ws + WS_C3I);
  float* wT  = (float*)(ws + WS_WT);

  prep_kernel<<<COUT, 192, 0, stream>>>(w, cb, gamma, beta, mean, var, Bg, bsh, wT);
  conv_mfma_kernel<<<dim3(WW/16, HH/16, BATCH), 512, LDS_CONV, stream>>>(x, Bg, bsh, top1);
  select_kernel<<<BATCH, SNT, 0, stream>>>(top1, cidx);
  refine_kernel<<<dim3(CAND, BATCH), COUT, 0, stream>>>(x, wT, cb, gamma, beta, mean, var,
                                                        cidx, ck, c3v, c3i);
  final_kernel<<<BATCH, 256, 0, stream>>>(ck, cidx, c3v, c3i, out);
}